// Round 1
// 332.247 us; speedup vs baseline: 1.0294x; 1.0294x over previous
//
#include <hip/hip_runtime.h>
#include <math.h>

// Problem constants (fixed by the reference)
#define N_NODES 1024
#define BATCH   8
#define FEAT    128        // F == O
#define NDIR    3
#define NB      (N_NODES*BATCH)   // 8192
#define G3      384               // 3*O

typedef __bf16 bf16_t;
using bf16x8 = __attribute__((ext_vector_type(8))) __bf16;
using bf16x4 = __attribute__((ext_vector_type(4))) __bf16;
using f32x4  = __attribute__((ext_vector_type(4))) float;

// async global->LDS 16B per lane; LDS dest must be wave-uniform base (+lane*16)
#define GLOAD_LDS16(g, l) \
    __builtin_amdgcn_global_load_lds((const __attribute__((address_space(1))) void*)(g), \
                                     (__attribute__((address_space(3))) void*)(l), 16, 0, 0)

// ---------------------------------------------------------------------------
// Tiled MFMA GEMM helpers, 4 waves as 2x2 (wr=w>>1, wc=w&1).
// LDS tiles are [R rows][64 k] bf16, k-contiguous (128 B per row).
// stage_op<R>: stage one 64-k chunk of an R-row operand. Each wave-call
// writes 1024 contiguous bytes (8 rows); wave w owns rows [w*R/4, (w+1)*R/4).
// ---------------------------------------------------------------------------
template<int R>
__device__ __forceinline__ void stage_op(const bf16_t* __restrict__ src, int stride,
                                         int k0, bf16_t* lds, int w, int lane)
{
    #pragma unroll
    for (int q = 0; q < R/32; ++q) {
        int rbase = w*(R/4) + q*8;                 // wave-uniform
        int row = rbase + (lane >> 3);
        int seg = lane & 7;
        GLOAD_LDS16(src + (size_t)row*stride + k0 + seg*8,
                    (char*)lds + (size_t)rbase*128);
    }
}

// mfma_tile<MI,NJ>: wave computes MI x NJ 16x16 fragments over one 64-k chunk.
// A rows for wave: wr*MI*16 .. ; B rows: wc*NJ*16 .. .
template<int MI, int NJ>
__device__ __forceinline__ void mfma_tile(const bf16_t* As, const bf16_t* Bs,
                                          f32x4 (&acc)[MI][NJ], int wr, int wc, int lane)
{
    #pragma unroll
    for (int ks = 0; ks < 64; ks += 32) {
        bf16x8 af[MI], bf[NJ];
        #pragma unroll
        for (int i = 0; i < MI; ++i)
            af[i] = *reinterpret_cast<const bf16x8*>(
                &As[(wr*MI*16 + i*16 + (lane & 15))*64 + ks + ((lane >> 4) * 8)]);
        #pragma unroll
        for (int j = 0; j < NJ; ++j)
            bf[j] = *reinterpret_cast<const bf16x8*>(
                &Bs[(wc*NJ*16 + j*16 + (lane & 15))*64 + ks + ((lane >> 4) * 8)]);
        #pragma unroll
        for (int i = 0; i < MI; ++i) {
            #pragma unroll
            for (int j = 0; j < NJ; ++j)
                acc[i][j] = __builtin_amdgcn_mfma_f32_16x16x32_bf16(af[i], bf[j], acc[i][j], 0, 0, 0);
        }
    }
}

// ---------------------------------------------------------------------------
// adj fp32 -> CENTERED bf16 (adj - 0.5): halves quantization abs error.
// ---------------------------------------------------------------------------
__global__ __launch_bounds__(256) void k_cvt_adj(
    const float* __restrict__ src, bf16_t* __restrict__ dst, int n4)
{
    int i = blockIdx.x * 256 + threadIdx.x;
    int stride = gridDim.x * 256;
    for (; i < n4; i += stride) {
        float4 v = reinterpret_cast<const float4*>(src)[i];
        bf16x4 o;
        o[0] = (bf16_t)(v.x - 0.5f); o[1] = (bf16_t)(v.y - 0.5f);
        o[2] = (bf16_t)(v.z - 0.5f); o[3] = (bf16_t)(v.w - 0.5f);
        *reinterpret_cast<bf16x4*>(&dst[(size_t)i * 4]) = o;
    }
}

// ---------------------------------------------------------------------------
// Weight prep, hi/lo split concats (K'=384):
//  m<384: W -> wsup rows 0-383 (pattern A [hi|lo|hi])
//  m in [384,512): Wh -> wsup rows 384-511 (A)
//  m in [512,896): Whh -> wsup rows 512-895 (A)   [merged k_gh weights]
//  m in [896,1280): Wih -> wihc (B [hi|hi|lo])
// wsup: [2][896][384]
// ---------------------------------------------------------------------------
__global__ __launch_bounds__(128) void k_wprep(
    const float* __restrict__ W, const float* __restrict__ Wh,
    const float* __restrict__ Whh, const float* __restrict__ Wih,
    bf16_t* __restrict__ wsup,    // [2][896][384]
    bf16_t* __restrict__ wihc)    // [2][384][384]
{
    int m = blockIdx.x, l = blockIdx.y, k = threadIdx.x;
    float w;
    bf16_t* dst;
    bool patB = false;
    if (m < 384) {
        int d = m >> 7, o = m & 127;
        w = W[((size_t)(l*3 + d)*128 + k)*128 + o];
        dst = wsup + ((size_t)l*896 + m)*384;
    } else if (m < 512) {
        int o = m - 384;
        w = Wh[((size_t)l*128 + k)*128 + o];
        dst = wsup + ((size_t)l*896 + m)*384;
    } else if (m < 896) {
        int c = m - 512;
        w = Whh[((size_t)l*384 + c)*128 + k];
        dst = wsup + ((size_t)l*896 + m)*384;
    } else {
        int c = m - 896;
        w = Wih[((size_t)l*384 + c)*128 + k];
        dst = wihc + ((size_t)l*384 + c)*384;
        patB = true;
    }
    bf16_t hi = (bf16_t)w;
    bf16_t lo = (bf16_t)(w - (float)hi);
    if (patB) { dst[k] = hi; dst[128 + k] = hi; dst[256 + k] = lo; }
    else      { dst[k] = hi; dst[128 + k] = lo; dst[256 + k] = hi; }
}

// ---------------------------------------------------------------------------
// x-cat build (layer 0): inputs fp32 [N,B,128] -> xcat [8][1024][384] = [hi|hi|lo]
// ---------------------------------------------------------------------------
__global__ __launch_bounds__(256) void k_xcat(
    const float* __restrict__ X, bf16_t* __restrict__ xcat)
{
    int idx = blockIdx.x * 256 + threadIdx.x;   // over 8192*128
    int k = idx & 127, r = idx >> 7;
    int n = r >> 3, b = r & 7;
    float v = X[idx];
    bf16_t hi = (bf16_t)v;
    bf16_t lo = (bf16_t)(v - (float)hi);
    bf16_t* dst = xcat + ((size_t)(b*1024 + n))*384 + k;
    dst[0] = hi; dst[128] = hi; dst[256] = lo;
}

// ---------------------------------------------------------------------------
// k_sup2 (128x128 tiles): C[m][n] = sum_k' wcat[m][k'] * xcat[b][n][k']  (K'=384)
//  m<384 : supt[((m>>7)*8+b)*128 + (m&127)][n] = bf16(C + Bc)
//  m in [384,512): tbuf[(b*128 + m-384)][n] = relu(C + Bh)  (fp32)
//  m>=512: ghb[(b*1024+n)][m-512] = bf16(C + bhh)           [merged k_gh]
// grid (8 n-tiles, 7 m-tiles, 8 b)
// ---------------------------------------------------------------------------
__global__ __launch_bounds__(256, 2) void k_sup2(
    const bf16_t* __restrict__ Wcat,  // [896][384] (layer slice)
    const bf16_t* __restrict__ xcat,  // [8][1024][384]
    const float* __restrict__ Bcl,    // [3,128]
    const float* __restrict__ Bhl,    // [128]
    const float* __restrict__ bhhl,   // [384]
    bf16_t* __restrict__ supt,        // [24][128][1024]
    float* __restrict__ tbuf,         // [8][128][1024]
    bf16_t* __restrict__ ghb)         // [8192][384]
{
    __shared__ bf16_t As[128*64];
    __shared__ bf16_t Bs[128*64];
    const int t = threadIdx.x, lane = t & 63, w = t >> 6;
    const int wr = w >> 1, wc = w & 1;
    const int n0 = blockIdx.x * 128;
    const int m0 = blockIdx.y * 128;
    const int b  = blockIdx.z;
    const bf16_t* Arow = Wcat + (size_t)m0 * 384;
    const bf16_t* Brow = xcat + ((size_t)b * 1024 + n0) * 384;

    f32x4 acc[4][4] = {};
    for (int k0 = 0; k0 < 384; k0 += 64) {
        stage_op<128>(Arow, 384, k0, As, w, lane);
        stage_op<128>(Brow, 384, k0, Bs, w, lane);
        __syncthreads();
        mfma_tile<4,4>(As, Bs, acc, wr, wc, lane);
        __syncthreads();
    }
    #pragma unroll
    for (int i = 0; i < 4; ++i) {
        // 4 consecutive output rows mb..mb+3 (category uniform: boundaries %16==0)
        int mb = m0 + wr*64 + i*16 + ((lane >> 4) * 4);
        #pragma unroll
        for (int j = 0; j < 4; ++j) {
            int n = n0 + wc*64 + j*16 + (lane & 15);
            if (mb < 384) {
                #pragma unroll
                for (int rg = 0; rg < 4; ++rg) {
                    int m = mb + rg;
                    int d = m >> 7, o = m & 127;
                    supt[((size_t)((d*8 + b)*128 + o))*1024 + n] =
                        (bf16_t)(acc[i][j][rg] + Bcl[d*128 + o]);
                }
            } else if (mb < 512) {
                #pragma unroll
                for (int rg = 0; rg < 4; ++rg) {
                    int o = mb + rg - 384;
                    tbuf[((size_t)(b*128 + o))*1024 + n] =
                        fmaxf(acc[i][j][rg] + Bhl[o], 0.0f);
                }
            } else {
                int c = mb - 512;
                bf16x4 pk;
                #pragma unroll
                for (int rg = 0; rg < 4; ++rg)
                    pk[rg] = (bf16_t)(acc[i][j][rg] + bhhl[c + rg]);
                *reinterpret_cast<bf16x4*>(&ghb[((size_t)(b*1024 + n))*384 + c]) = pk;
            }
        }
    }
}

// ---------------------------------------------------------------------------
// colsum[row] = sum_n supt[row][n]  (row = z*128+o, 3072 rows), fp32.
// ---------------------------------------------------------------------------
__global__ __launch_bounds__(256) void k_colsum(
    const bf16_t* __restrict__ supt, float* __restrict__ colsum)
{
    int row = blockIdx.x * 4 + (threadIdx.x >> 6);
    int lane = threadIdx.x & 63;
    const bf16_t* p = supt + (size_t)row * 1024 + lane * 16;
    bf16x8 v0 = *reinterpret_cast<const bf16x8*>(p);
    bf16x8 v1 = *reinterpret_cast<const bf16x8*>(p + 8);
    float s = 0.0f;
    #pragma unroll
    for (int i = 0; i < 8; ++i) s += (float)v0[i] + (float)v1[i];
    #pragma unroll
    for (int off = 32; off > 0; off >>= 1) s += __shfl_down(s, off, 64);
    if (lane == 0) colsum[row] = s;
}

// ---------------------------------------------------------------------------
// k_agg (64x128 tiles, adj read exactly ONCE):
//   agg[z][m][o] = sum_n adjc[z][m][n]*supt[z][o][n] + 0.5*colsum
// Output aggcat [24576][384] = [hi|lo|hi]. grid (16 m-tiles, 24 z)
// ---------------------------------------------------------------------------
__global__ __launch_bounds__(256, 2) void k_agg(
    const bf16_t* __restrict__ adjb,   // [24][1024][1024] centered
    const bf16_t* __restrict__ supt,   // [24][128][1024]
    const float* __restrict__ colsum,  // [24][128]
    bf16_t* __restrict__ aggcat)       // [24576][384]
{
    __shared__ bf16_t As[64*64];
    __shared__ bf16_t Bs[128*64];
    const int t = threadIdx.x, lane = t & 63, w = t >> 6;
    const int wr = w >> 1, wc = w & 1;
    const int m0 = blockIdx.x * 64;
    const int z  = blockIdx.y;
    const bf16_t* Arow = adjb + (size_t)z * 1024 * 1024 + (size_t)m0 * 1024;
    const bf16_t* Brow = supt + (size_t)z * 128 * 1024;

    f32x4 acc[2][4] = {};
    for (int k0 = 0; k0 < 1024; k0 += 64) {
        stage_op<64>(Arow, 1024, k0, As, w, lane);
        stage_op<128>(Brow, 1024, k0, Bs, w, lane);
        __syncthreads();
        mfma_tile<2,4>(As, Bs, acc, wr, wc, lane);
        __syncthreads();
    }
    #pragma unroll
    for (int i = 0; i < 2; ++i) {
        #pragma unroll
        for (int rg = 0; rg < 4; ++rg) {
            size_t m = (size_t)z*1024 + m0 + wr*32 + i*16 + ((lane >> 4) * 4) + rg;
            bf16_t* row = aggcat + m*384;
            #pragma unroll
            for (int j = 0; j < 4; ++j) {
                int o = wc*64 + j*16 + (lane & 15);
                float v = acc[i][j][rg] + 0.5f * colsum[z*128 + o];
                bf16_t hi = (bf16_t)v;
                bf16_t lo = (bf16_t)(v - (float)hi);
                row[o] = hi; row[128 + o] = lo; row[256 + o] = hi;
            }
        }
    }
}

// ---------------------------------------------------------------------------
// k_gi (128x128 tiles): gi[m][c] = sum_k' aggcat[m][k']*wihc[c][k'] + bih[c]
// c<256 -> girz bf16; c>=256 -> gin fp32. grid (192 m-tiles, 3 c-tiles).
// ---------------------------------------------------------------------------
__global__ __launch_bounds__(256, 2) void k_gi(
    const bf16_t* __restrict__ A,      // [24576][384]
    const bf16_t* __restrict__ B,      // [384][384]
    const float*  __restrict__ bias,   // [384]
    bf16_t* __restrict__ girz,         // [24576][256]
    float* __restrict__ gin)           // [24576][128]
{
    __shared__ bf16_t As[128*64];
    __shared__ bf16_t Bs[128*64];
    const int t = threadIdx.x, lane = t & 63, w = t >> 6;
    const int wr = w >> 1, wc = w & 1;
    const int m0 = blockIdx.x * 128;
    const int c0 = blockIdx.y * 128;
    const bf16_t* Arow = A + (size_t)m0 * 384;
    const bf16_t* Brow = B + (size_t)c0 * 384;

    f32x4 acc[4][4] = {};
    for (int k0 = 0; k0 < 384; k0 += 64) {
        stage_op<128>(Arow, 384, k0, As, w, lane);
        stage_op<128>(Brow, 384, k0, Bs, w, lane);
        __syncthreads();
        mfma_tile<4,4>(As, Bs, acc, wr, wc, lane);
        __syncthreads();
    }
    #pragma unroll
    for (int j = 0; j < 4; ++j) {
        int c = c0 + wc*64 + j*16 + (lane & 15);
        float bv = bias[c];
        #pragma unroll
        for (int i = 0; i < 4; ++i) {
            #pragma unroll
            for (int rg = 0; rg < 4; ++rg) {
                int m = m0 + wr*64 + i*16 + ((lane >> 4) * 4) + rg;
                float v = acc[i][j][rg] + bv;
                if (c < 256) girz[(size_t)m*256 + c] = (bf16_t)v;
                else         gin[(size_t)m*128 + (c - 256)] = v;
            }
        }
    }
}

// ---------------------------------------------------------------------------
// GRU gates + sum over d + relu + highway blend.
// h reconstructed exactly from xcat (hi+lo). grid (64 n-blocks of 16, 8 b).
// ---------------------------------------------------------------------------
__global__ __launch_bounds__(256) void k_gates(
    const bf16_t* __restrict__ girz, const float* __restrict__ gin,
    const bf16_t* __restrict__ ghb,
    bf16_t* xcat,                       // NOT restrict: read+write same buffer
    const float* __restrict__ tbuf,
    float* __restrict__ Xout, int write_xcat)
{
    __shared__ float ts[128*17];
    const int b = blockIdx.y, n0 = blockIdx.x * 16;
    const int tid = threadIdx.x;
    {
        int o = tid >> 1, nh = (tid & 1) * 8;
        const float* src = tbuf + ((size_t)(b*128 + o))*1024 + n0 + nh;
        float4 v0 = *reinterpret_cast<const float4*>(src);
        float4 v1 = *reinterpret_cast<const float4*>(src + 4);
        float* dst = &ts[o*17 + nh];
        dst[0]=v0.x; dst[1]=v0.y; dst[2]=v0.z; dst[3]=v0.w;
        dst[4]=v1.x; dst[5]=v1.y; dst[6]=v1.z; dst[7]=v1.w;
    }
    __syncthreads();
    #pragma unroll
    for (int p = 0; p < 8; ++p) {
        int e = p*256 + tid;
        int nn = e >> 7, o = e & 127;
        int n = n0 + nn;
        size_t rb = (size_t)(b*1024 + n);
        bf16_t* xr = xcat + rb*384;
        float h = (float)xr[o] + (float)xr[256 + o];
        const bf16_t* ghr = ghb + rb*G3;
        float g_r = (float)ghr[o], g_z = (float)ghr[128+o], g_n = (float)ghr[256+o];
        float acc = 0.0f;
        #pragma unroll
        for (int d = 0; d < 3; ++d) {
            size_t rr = (size_t)((d*8 + b)*1024 + n);
            float i_r = (float)girz[rr*256 + o];
            float i_z = (float)girz[rr*256 + 128 + o];
            float i_n = gin[rr*128 + o];
            float rg = 1.0f / (1.0f + expf(-(i_r + g_r)));
            float zg = 1.0f / (1.0f + expf(-(i_z + g_z)));
            float ng = tanhf(i_n + rg * g_n);
            acc += (1.0f - zg) * ng + zg * h;
        }
        float outv = fmaxf(acc, 0.0f);
        float tg = ts[o*17 + nn];
        float res = outv * tg + h * (1.0f - tg);
        if (Xout) Xout[(size_t)(n*8 + b)*128 + o] = res;
        if (write_xcat) {
            bf16_t hi = (bf16_t)res;
            bf16_t lo = (bf16_t)(res - (float)hi);
            xr[o] = hi; xr[128 + o] = hi; xr[256 + o] = lo;
        }
    }
}

// ---------------------------------------------------------------------------
extern "C" void kernel_launch(void* const* d_in, const int* in_sizes, int n_in,
                              void* d_out, int out_size, void* d_ws, size_t ws_size,
                              hipStream_t stream) {
    const float* inputs = (const float*)d_in[0];   // [1024,8,128]
    const float* adj    = (const float*)d_in[1];   // [3,8,1024,1024]
    const float* W      = (const float*)d_in[2];   // [2,3,128,128]
    const float* Bc     = (const float*)d_in[3];   // [2,3,128]
    const float* Wh     = (const float*)d_in[4];   // [2,128,128]
    const float* Bh     = (const float*)d_in[5];   // [2,128]
    const float* Wih    = (const float*)d_in[6];   // [2,384,128]
    const float* Whh    = (const float*)d_in[7];   // [2,384,128]
    const float* bih    = (const float*)d_in[8];   // [2,384]
    const float* bhh    = (const float*)d_in[9];   // [2,384]

    char* ws = (char*)d_ws;
    float*  tbuf   = (float*)ws;   ws += (size_t)8*128*1024*4;      // 4.19 MB
    bf16_t* xcat   = (bf16_t*)ws;  ws += (size_t)8*1024*384*2;      // 6.29 MB
    bf16_t* ghb    = (bf16_t*)ws;  ws += (size_t)NB*G3*2;           // 6.29 MB
    bf16_t* supt   = (bf16_t*)ws;  ws += (size_t)24*128*1024*2;     // 6.29 MB
    bf16_t* aggcat = (bf16_t*)ws;  ws += (size_t)3*NB*384*2;        // 18.87 MB
    bf16_t* girz   = (bf16_t*)ws;  ws += (size_t)3*NB*256*2;        // 12.58 MB
    float*  gin    = (float*)ws;   ws += (size_t)3*NB*128*4;        // 12.58 MB
    float*  colsum = (float*)ws;   ws += (size_t)24*128*4;          // 12 KB
    bf16_t* wsup   = (bf16_t*)ws;  ws += (size_t)2*896*384*2;       // 1.38 MB
    bf16_t* wihc   = (bf16_t*)ws;  ws += (size_t)2*384*384*2;       // 1.18 MB
    bf16_t* adjb   = (bf16_t*)ws;                                   // 50.33 MB

    // one-time preps
    k_cvt_adj<<<dim3(4096), dim3(256), 0, stream>>>(adj, adjb, 3*8*1024*1024/4);
    k_wprep<<<dim3(1280, 2), dim3(128), 0, stream>>>(W, Wh, Whh, Wih, wsup, wihc);
    k_xcat<<<dim3(4096), dim3(256), 0, stream>>>(inputs, xcat);

    for (int l = 0; l < 2; ++l) {
        // support (bf16 [z][o][n]) + highway t (fp32 [b][o][n]) + gh (merged)
        k_sup2<<<dim3(8, 7, 8), dim3(256), 0, stream>>>(
            wsup + (size_t)l*896*384, xcat, Bc + l*3*128, Bh + l*128, bhh + l*G3,
            supt, tbuf, ghb);
        // column sums of support (for centered-adj correction)
        k_colsum<<<dim3(768), dim3(256), 0, stream>>>(supt, colsum);
        // agg = adjc @ support + 0.5*colsum, output hi/lo-cat (adj read once)
        k_agg<<<dim3(16, 24), dim3(256), 0, stream>>>(adjb, supt, colsum, aggcat);
        // gi = agg @ Wih^T + bih (K'=384)
        k_gi<<<dim3(192, 3), dim3(256), 0, stream>>>(
            aggcat, wihc + (size_t)l*384*384, bih + l*G3, girz, gin);
        // gates + sum_d + relu + highway; layer0 -> xcat update, layer1 -> d_out
        k_gates<<<dim3(64, 8), dim3(256), 0, stream>>>(
            girz, gin, ghb, xcat, tbuf,
            (l == 1) ? (float*)d_out : (float*)nullptr, (l == 0) ? 1 : 0);
    }
}

// Round 2
// 331.928 us; speedup vs baseline: 1.0304x; 1.0010x over previous
//
#include <hip/hip_runtime.h>
#include <math.h>

// Problem constants (fixed by the reference)
#define N_NODES 1024
#define BATCH   8
#define FEAT    128        // F == O
#define NDIR    3
#define NB      (N_NODES*BATCH)   // 8192
#define G3      384               // 3*O

typedef __bf16 bf16_t;
using bf16x8 = __attribute__((ext_vector_type(8))) __bf16;
using bf16x4 = __attribute__((ext_vector_type(4))) __bf16;
using f32x4  = __attribute__((ext_vector_type(4))) float;

// async global->LDS 16B per lane; LDS dest must be wave-uniform base (+lane*16)
#define GLOAD_LDS16(g, l) \
    __builtin_amdgcn_global_load_lds((const __attribute__((address_space(1))) void*)(g), \
                                     (__attribute__((address_space(3))) void*)(l), 16, 0, 0)

// ---------------------------------------------------------------------------
// Tiled MFMA GEMM helpers, 4 waves as 2x2 (wr=w>>1, wc=w&1).
// LDS tiles are [R rows][64 k] bf16 (128 B rows) with an XOR-swizzle on the
// 16B slot index: content of (row, slot) = global (row, slot ^ (row&7)).
// Rationale: linear [R][64] rows put 16 lanes of a quarter-wave in the same
// bank quad (16-way conflict on ds_read_b128). The swizzle spreads 8
// consecutive rows across all 8 slots -> 2-way (free).
// global_load_lds writes linearly (base+lane*16), so the swizzle is applied
// by permuting the per-lane GLOBAL source address (rule: both-sides-or-never).
// ---------------------------------------------------------------------------
template<int R>
__device__ __forceinline__ void stage_swz(const bf16_t* __restrict__ src, int stride,
                                          int k0, bf16_t* lds, int w, int lane)
{
    #pragma unroll
    for (int q = 0; q < R/32; ++q) {
        int rbase = w*(R/4) + q*8;                 // wave-uniform
        int row = rbase + (lane >> 3);
        int seg = (lane & 7) ^ (row & 7);          // pre-swizzled source slot
        GLOAD_LDS16(src + (size_t)row*stride + k0 + seg*8,
                    (char*)lds + (size_t)rbase*128);
    }
}

// fp32 A-operand stage (layer-0 k_agg): load adj fp32, center to bf16,
// ds_write the swizzled slot, and write the LINEAR tile to adjb for layer 1.
__device__ __forceinline__ void stageA_f32(const float* __restrict__ src, int k0,
                                           bf16_t* lds, bf16_t* __restrict__ gout,
                                           int w, int lane)
{
    #pragma unroll
    for (int q = 0; q < 2; ++q) {
        int rbase = w*16 + q*8;
        int row = rbase + (lane >> 3);
        int s   = lane & 7;                        // LDS slot this lane fills
        int seg = s ^ (row & 7);                   // source slot for that content
        const float* g = src + (size_t)row*1024 + k0 + seg*8;
        float4 v0 = *reinterpret_cast<const float4*>(g);
        float4 v1 = *reinterpret_cast<const float4*>(g + 4);
        bf16x8 pk;
        pk[0]=(bf16_t)(v0.x-0.5f); pk[1]=(bf16_t)(v0.y-0.5f);
        pk[2]=(bf16_t)(v0.z-0.5f); pk[3]=(bf16_t)(v0.w-0.5f);
        pk[4]=(bf16_t)(v1.x-0.5f); pk[5]=(bf16_t)(v1.y-0.5f);
        pk[6]=(bf16_t)(v1.z-0.5f); pk[7]=(bf16_t)(v1.w-0.5f);
        *reinterpret_cast<bf16x8*>(&lds[row*64 + s*8]) = pk;                 // swizzled
        *reinterpret_cast<bf16x8*>(gout + (size_t)row*1024 + k0 + seg*8) = pk; // linear
    }
}

// mfma over one 64-k chunk, reading swizzled LDS.
template<int MI, int NJ>
__device__ __forceinline__ void mfma_swz(const bf16_t* As, const bf16_t* Bs,
                                         f32x4 (&acc)[MI][NJ], int wr, int wc, int lane)
{
    #pragma unroll
    for (int ks = 0; ks < 64; ks += 32) {
        int bslot = ks/8 + (lane >> 4);            // linear slot pre-XOR
        int sx = bslot ^ (lane & 7);               // row&7 == lane&7 for all frags
        bf16x8 af[MI], bfv[NJ];
        #pragma unroll
        for (int i = 0; i < MI; ++i) {
            int row = wr*MI*16 + i*16 + (lane & 15);
            af[i] = *reinterpret_cast<const bf16x8*>(&As[row*64 + sx*8]);
        }
        #pragma unroll
        for (int j = 0; j < NJ; ++j) {
            int row = wc*NJ*16 + j*16 + (lane & 15);
            bfv[j] = *reinterpret_cast<const bf16x8*>(&Bs[row*64 + sx*8]);
        }
        #pragma unroll
        for (int i = 0; i < MI; ++i) {
            #pragma unroll
            for (int j = 0; j < NJ; ++j)
                acc[i][j] = __builtin_amdgcn_mfma_f32_16x16x32_bf16(af[i], bfv[j], acc[i][j], 0, 0, 0);
        }
    }
}

// ---------------------------------------------------------------------------
// Weight prep, hi/lo split concats (K'=384):
//  m<384: W -> wsup rows 0-383 (pattern A [hi|lo|hi])
//  m in [384,512): Wh -> wsup rows 384-511 (A)
//  m in [512,896): Whh -> wsup rows 512-895 (A)   [merged k_gh weights]
//  m in [896,1280): Wih -> wihc (B [hi|hi|lo])
// ---------------------------------------------------------------------------
__global__ __launch_bounds__(128) void k_wprep(
    const float* __restrict__ W, const float* __restrict__ Wh,
    const float* __restrict__ Whh, const float* __restrict__ Wih,
    bf16_t* __restrict__ wsup,    // [2][896][384]
    bf16_t* __restrict__ wihc)    // [2][384][384]
{
    int m = blockIdx.x, l = blockIdx.y, k = threadIdx.x;
    float w;
    bf16_t* dst;
    bool patB = false;
    if (m < 384) {
        int d = m >> 7, o = m & 127;
        w = W[((size_t)(l*3 + d)*128 + k)*128 + o];
        dst = wsup + ((size_t)l*896 + m)*384;
    } else if (m < 512) {
        int o = m - 384;
        w = Wh[((size_t)l*128 + k)*128 + o];
        dst = wsup + ((size_t)l*896 + m)*384;
    } else if (m < 896) {
        int c = m - 512;
        w = Whh[((size_t)l*384 + c)*128 + k];
        dst = wsup + ((size_t)l*896 + m)*384;
    } else {
        int c = m - 896;
        w = Wih[((size_t)l*384 + c)*128 + k];
        dst = wihc + ((size_t)l*384 + c)*384;
        patB = true;
    }
    bf16_t hi = (bf16_t)w;
    bf16_t lo = (bf16_t)(w - (float)hi);
    if (patB) { dst[k] = hi; dst[128 + k] = hi; dst[256 + k] = lo; }
    else      { dst[k] = hi; dst[128 + k] = lo; dst[256 + k] = hi; }
}

// ---------------------------------------------------------------------------
// x-cat build (layer 0): inputs fp32 [N,B,128] -> xcat [8][1024][384] = [hi|hi|lo]
// ---------------------------------------------------------------------------
__global__ __launch_bounds__(256) void k_xcat(
    const float* __restrict__ X, bf16_t* __restrict__ xcat)
{
    int idx = blockIdx.x * 256 + threadIdx.x;   // over 8192*128
    int k = idx & 127, r = idx >> 7;
    int n = r >> 3, b = r & 7;
    float v = X[idx];
    bf16_t hi = (bf16_t)v;
    bf16_t lo = (bf16_t)(v - (float)hi);
    bf16_t* dst = xcat + ((size_t)(b*1024 + n))*384 + k;
    dst[0] = hi; dst[128] = hi; dst[256] = lo;
}

// ---------------------------------------------------------------------------
// k_sup2 (128x128 tiles, 2-phase dbuf): C[m][n] = sum_k' wcat[m][k']*xcat[b][n][k']
//  m<384 : supt; m in [384,512): tbuf (relu); m>=512: ghb (merged k_gh)
// grid (8 n-tiles, 7 m-tiles, 8 b)
// ---------------------------------------------------------------------------
__global__ __launch_bounds__(256, 2) void k_sup2(
    const bf16_t* __restrict__ Wcat,  // [896][384] (layer slice)
    const bf16_t* __restrict__ xcat,  // [8][1024][384]
    const float* __restrict__ Bcl,    // [3,128]
    const float* __restrict__ Bhl,    // [128]
    const float* __restrict__ bhhl,   // [384]
    bf16_t* __restrict__ supt,        // [24][128][1024]
    float* __restrict__ tbuf,         // [8][128][1024]
    bf16_t* __restrict__ ghb)         // [8192][384]
{
    __shared__ bf16_t As[2][128*64];
    __shared__ bf16_t Bs[2][128*64];
    const int t = threadIdx.x, lane = t & 63, w = t >> 6;
    const int wr = w >> 1, wc = w & 1;
    const int n0 = blockIdx.x * 128;
    const int m0 = blockIdx.y * 128;
    const int b  = blockIdx.z;
    const bf16_t* Arow = Wcat + (size_t)m0 * 384;
    const bf16_t* Brow = xcat + ((size_t)b * 1024 + n0) * 384;

    f32x4 acc[4][4] = {};
    stage_swz<128>(Arow, 384, 0, As[0], w, lane);
    stage_swz<128>(Brow, 384, 0, Bs[0], w, lane);
    __syncthreads();
    #pragma unroll
    for (int kt = 0; kt < 6; ++kt) {
        if (kt + 1 < 6) {
            stage_swz<128>(Arow, 384, (kt+1)*64, As[(kt+1)&1], w, lane);
            stage_swz<128>(Brow, 384, (kt+1)*64, Bs[(kt+1)&1], w, lane);
        }
        mfma_swz<4,4>(As[kt&1], Bs[kt&1], acc, wr, wc, lane);
        __syncthreads();   // drains prefetch loads (issued before MFMA) + LDS reads
    }
    #pragma unroll
    for (int i = 0; i < 4; ++i) {
        int mb = m0 + wr*64 + i*16 + ((lane >> 4) * 4);
        #pragma unroll
        for (int j = 0; j < 4; ++j) {
            int n = n0 + wc*64 + j*16 + (lane & 15);
            if (mb < 384) {
                #pragma unroll
                for (int rg = 0; rg < 4; ++rg) {
                    int m = mb + rg;
                    int d = m >> 7, o = m & 127;
                    supt[((size_t)((d*8 + b)*128 + o))*1024 + n] =
                        (bf16_t)(acc[i][j][rg] + Bcl[d*128 + o]);
                }
            } else if (mb < 512) {
                #pragma unroll
                for (int rg = 0; rg < 4; ++rg) {
                    int o = mb + rg - 384;
                    tbuf[((size_t)(b*128 + o))*1024 + n] =
                        fmaxf(acc[i][j][rg] + Bhl[o], 0.0f);
                }
            } else {
                int c = mb - 512;
                bf16x4 pk;
                #pragma unroll
                for (int rg = 0; rg < 4; ++rg)
                    pk[rg] = (bf16_t)(acc[i][j][rg] + bhhl[c + rg]);
                *reinterpret_cast<bf16x4*>(&ghb[((size_t)(b*1024 + n))*384 + c]) = pk;
            }
        }
    }
}

// ---------------------------------------------------------------------------
// colsum[row] = sum_n supt[row][n]  (row = z*128+o, 3072 rows), fp32.
// ---------------------------------------------------------------------------
__global__ __launch_bounds__(256) void k_colsum(
    const bf16_t* __restrict__ supt, float* __restrict__ colsum)
{
    int row = blockIdx.x * 4 + (threadIdx.x >> 6);
    int lane = threadIdx.x & 63;
    const bf16_t* p = supt + (size_t)row * 1024 + lane * 16;
    bf16x8 v0 = *reinterpret_cast<const bf16x8*>(p);
    bf16x8 v1 = *reinterpret_cast<const bf16x8*>(p + 8);
    float s = 0.0f;
    #pragma unroll
    for (int i = 0; i < 8; ++i) s += (float)v0[i] + (float)v1[i];
    #pragma unroll
    for (int off = 32; off > 0; off >>= 1) s += __shfl_down(s, off, 64);
    if (lane == 0) colsum[row] = s;
}

// ---------------------------------------------------------------------------
// k_agg (64x128 tiles, 2-phase dbuf, adj read exactly ONCE):
//   agg[z][m][o] = sum_n adjc[z][m][n]*supt[z][o][n] + 0.5*colsum
// AMODE=1 (layer 0): A staged from adj fp32 (centered on the fly), converted
//   tiles ALSO written to adjb (linear) for layer 1.  AMODE=0: gload from adjb.
// Output aggcat [24576][384] = [hi|lo|hi]. grid (16 m-tiles, 24 z)
// ---------------------------------------------------------------------------
template<int AMODE>
__global__ __launch_bounds__(256, 2) void k_agg(
    const float* __restrict__ adjf,    // [24][1024][1024] fp32 (AMODE=1)
    bf16_t* __restrict__ adjb,         // [24][1024][1024] centered bf16
    const bf16_t* __restrict__ supt,   // [24][128][1024]
    const float* __restrict__ colsum,  // [24][128]
    bf16_t* __restrict__ aggcat)       // [24576][384]
{
    __shared__ bf16_t As[2][64*64];
    __shared__ bf16_t Bs[2][128*64];
    const int t = threadIdx.x, lane = t & 63, w = t >> 6;
    const int wr = w >> 1, wc = w & 1;
    const int m0 = blockIdx.x * 64;
    const int z  = blockIdx.y;
    const float*  Af = adjf + (size_t)z * 1024 * 1024 + (size_t)m0 * 1024;
    bf16_t*       Ab = adjb + (size_t)z * 1024 * 1024 + (size_t)m0 * 1024;
    const bf16_t* Brow = supt + (size_t)z * 128 * 1024;

    f32x4 acc[2][4] = {};
    if (AMODE) stageA_f32(Af, 0, As[0], Ab, w, lane);
    else       stage_swz<64>(Ab, 1024, 0, As[0], w, lane);
    stage_swz<128>(Brow, 1024, 0, Bs[0], w, lane);
    __syncthreads();
    #pragma unroll
    for (int kt = 0; kt < 16; ++kt) {
        if (kt + 1 < 16) {
            if (AMODE) stageA_f32(Af, (kt+1)*64, As[(kt+1)&1], Ab, w, lane);
            else       stage_swz<64>(Ab, 1024, (kt+1)*64, As[(kt+1)&1], w, lane);
            stage_swz<128>(Brow, 1024, (kt+1)*64, Bs[(kt+1)&1], w, lane);
        }
        mfma_swz<2,4>(As[kt&1], Bs[kt&1], acc, wr, wc, lane);
        __syncthreads();
    }
    #pragma unroll
    for (int i = 0; i < 2; ++i) {
        #pragma unroll
        for (int rg = 0; rg < 4; ++rg) {
            size_t m = (size_t)z*1024 + m0 + wr*32 + i*16 + ((lane >> 4) * 4) + rg;
            bf16_t* row = aggcat + m*384;
            #pragma unroll
            for (int j = 0; j < 4; ++j) {
                int o = wc*64 + j*16 + (lane & 15);
                float v = acc[i][j][rg] + 0.5f * colsum[z*128 + o];
                bf16_t hi = (bf16_t)v;
                bf16_t lo = (bf16_t)(v - (float)hi);
                row[o] = hi; row[128 + o] = lo; row[256 + o] = hi;
            }
        }
    }
}

// ---------------------------------------------------------------------------
// k_gi (128x128 tiles, 2-phase dbuf): gi[m][c] = sum_k' aggcat[m][k']*wihc[c][k']
// c<256 -> girz bf16; c>=256 -> gin fp32. grid (192 m-tiles, 3 c-tiles).
// ---------------------------------------------------------------------------
__global__ __launch_bounds__(256, 2) void k_gi(
    const bf16_t* __restrict__ A,      // [24576][384]
    const bf16_t* __restrict__ B,      // [384][384]
    const float*  __restrict__ bias,   // [384]
    bf16_t* __restrict__ girz,         // [24576][256]
    float* __restrict__ gin)           // [24576][128]
{
    __shared__ bf16_t As[2][128*64];
    __shared__ bf16_t Bs[2][128*64];
    const int t = threadIdx.x, lane = t & 63, w = t >> 6;
    const int wr = w >> 1, wc = w & 1;
    const int m0 = blockIdx.x * 128;
    const int c0 = blockIdx.y * 128;
    const bf16_t* Arow = A + (size_t)m0 * 384;
    const bf16_t* Brow = B + (size_t)c0 * 384;

    f32x4 acc[4][4] = {};
    stage_swz<128>(Arow, 384, 0, As[0], w, lane);
    stage_swz<128>(Brow, 384, 0, Bs[0], w, lane);
    __syncthreads();
    #pragma unroll
    for (int kt = 0; kt < 6; ++kt) {
        if (kt + 1 < 6) {
            stage_swz<128>(Arow, 384, (kt+1)*64, As[(kt+1)&1], w, lane);
            stage_swz<128>(Brow, 384, (kt+1)*64, Bs[(kt+1)&1], w, lane);
        }
        mfma_swz<4,4>(As[kt&1], Bs[kt&1], acc, wr, wc, lane);
        __syncthreads();
    }
    #pragma unroll
    for (int j = 0; j < 4; ++j) {
        int c = c0 + wc*64 + j*16 + (lane & 15);
        float bv = bias[c];
        #pragma unroll
        for (int i = 0; i < 4; ++i) {
            #pragma unroll
            for (int rg = 0; rg < 4; ++rg) {
                int m = m0 + wr*64 + i*16 + ((lane >> 4) * 4) + rg;
                float v = acc[i][j][rg] + bv;
                if (c < 256) girz[(size_t)m*256 + c] = (bf16_t)v;
                else         gin[(size_t)m*128 + (c - 256)] = v;
            }
        }
    }
}

// ---------------------------------------------------------------------------
// GRU gates + sum over d + relu + highway blend.
// h reconstructed exactly from xcat (hi+lo). grid (64 n-blocks of 16, 8 b).
// ---------------------------------------------------------------------------
__global__ __launch_bounds__(256) void k_gates(
    const bf16_t* __restrict__ girz, const float* __restrict__ gin,
    const bf16_t* __restrict__ ghb,
    bf16_t* xcat,                       // NOT restrict: read+write same buffer
    const float* __restrict__ tbuf,
    float* __restrict__ Xout, int write_xcat)
{
    __shared__ float ts[128*17];
    const int b = blockIdx.y, n0 = blockIdx.x * 16;
    const int tid = threadIdx.x;
    {
        int o = tid >> 1, nh = (tid & 1) * 8;
        const float* src = tbuf + ((size_t)(b*128 + o))*1024 + n0 + nh;
        float4 v0 = *reinterpret_cast<const float4*>(src);
        float4 v1 = *reinterpret_cast<const float4*>(src + 4);
        float* dst = &ts[o*17 + nh];
        dst[0]=v0.x; dst[1]=v0.y; dst[2]=v0.z; dst[3]=v0.w;
        dst[4]=v1.x; dst[5]=v1.y; dst[6]=v1.z; dst[7]=v1.w;
    }
    __syncthreads();
    #pragma unroll
    for (int p = 0; p < 8; ++p) {
        int e = p*256 + tid;
        int nn = e >> 7, o = e & 127;
        int n = n0 + nn;
        size_t rb = (size_t)(b*1024 + n);
        bf16_t* xr = xcat + rb*384;
        float h = (float)xr[o] + (float)xr[256 + o];
        const bf16_t* ghr = ghb + rb*G3;
        float g_r = (float)ghr[o], g_z = (float)ghr[128+o], g_n = (float)ghr[256+o];
        float acc = 0.0f;
        #pragma unroll
        for (int d = 0; d < 3; ++d) {
            size_t rr = (size_t)((d*8 + b)*1024 + n);
            float i_r = (float)girz[rr*256 + o];
            float i_z = (float)girz[rr*256 + 128 + o];
            float i_n = gin[rr*128 + o];
            float rg = 1.0f / (1.0f + expf(-(i_r + g_r)));
            float zg = 1.0f / (1.0f + expf(-(i_z + g_z)));
            float ng = tanhf(i_n + rg * g_n);
            acc += (1.0f - zg) * ng + zg * h;
        }
        float outv = fmaxf(acc, 0.0f);
        float tg = ts[o*17 + nn];
        float res = outv * tg + h * (1.0f - tg);
        if (Xout) Xout[(size_t)(n*8 + b)*128 + o] = res;
        if (write_xcat) {
            bf16_t hi = (bf16_t)res;
            bf16_t lo = (bf16_t)(res - (float)hi);
            xr[o] = hi; xr[128 + o] = hi; xr[256 + o] = lo;
        }
    }
}

// ---------------------------------------------------------------------------
extern "C" void kernel_launch(void* const* d_in, const int* in_sizes, int n_in,
                              void* d_out, int out_size, void* d_ws, size_t ws_size,
                              hipStream_t stream) {
    const float* inputs = (const float*)d_in[0];   // [1024,8,128]
    const float* adj    = (const float*)d_in[1];   // [3,8,1024,1024]
    const float* W      = (const float*)d_in[2];   // [2,3,128,128]
    const float* Bc     = (const float*)d_in[3];   // [2,3,128]
    const float* Wh     = (const float*)d_in[4];   // [2,128,128]
    const float* Bh     = (const float*)d_in[5];   // [2,128]
    const float* Wih    = (const float*)d_in[6];   // [2,384,128]
    const float* Whh    = (const float*)d_in[7];   // [2,384,128]
    const float* bih    = (const float*)d_in[8];   // [2,384]
    const float* bhh    = (const float*)d_in[9];   // [2,384]

    char* ws = (char*)d_ws;
    float*  tbuf   = (float*)ws;   ws += (size_t)8*128*1024*4;      // 4.19 MB
    bf16_t* xcat   = (bf16_t*)ws;  ws += (size_t)8*1024*384*2;      // 6.29 MB
    bf16_t* ghb    = (bf16_t*)ws;  ws += (size_t)NB*G3*2;           // 6.29 MB
    bf16_t* supt   = (bf16_t*)ws;  ws += (size_t)24*128*1024*2;     // 6.29 MB
    bf16_t* aggcat = (bf16_t*)ws;  ws += (size_t)3*NB*384*2;        // 18.87 MB
    bf16_t* girz   = (bf16_t*)ws;  ws += (size_t)3*NB*256*2;        // 12.58 MB
    float*  gin    = (float*)ws;   ws += (size_t)3*NB*128*4;        // 12.58 MB
    float*  colsum = (float*)ws;   ws += (size_t)24*128*4;          // 12 KB
    bf16_t* wsup   = (bf16_t*)ws;  ws += (size_t)2*896*384*2;       // 1.38 MB
    bf16_t* wihc   = (bf16_t*)ws;  ws += (size_t)2*384*384*2;       // 1.18 MB
    bf16_t* adjb   = (bf16_t*)ws;                                   // 50.33 MB

    // one-time preps (adj conversion now fused into layer-0 k_agg)
    k_wprep<<<dim3(1280, 2), dim3(128), 0, stream>>>(W, Wh, Whh, Wih, wsup, wihc);
    k_xcat<<<dim3(4096), dim3(256), 0, stream>>>(inputs, xcat);

    for (int l = 0; l < 2; ++l) {
        // support (bf16 [z][o][n]) + highway t (fp32 [b][o][n]) + gh (merged)
        k_sup2<<<dim3(8, 7, 8), dim3(256), 0, stream>>>(
            wsup + (size_t)l*896*384, xcat, Bc + l*3*128, Bh + l*128, bhh + l*G3,
            supt, tbuf, ghb);
        // column sums of support (for centered-adj correction)
        k_colsum<<<dim3(768), dim3(256), 0, stream>>>(supt, colsum);
        // agg = adjc @ support + 0.5*colsum; layer 0 converts adj on the fly
        if (l == 0)
            k_agg<1><<<dim3(16, 24), dim3(256), 0, stream>>>(adj, adjb, supt, colsum, aggcat);
        else
            k_agg<0><<<dim3(16, 24), dim3(256), 0, stream>>>(adj, adjb, supt, colsum, aggcat);
        // gi = agg @ Wih^T + bih (K'=384)
        k_gi<<<dim3(192, 3), dim3(256), 0, stream>>>(
            aggcat, wihc + (size_t)l*384*384, bih + l*G3, girz, gin);
        // gates + sum_d + relu + highway; layer0 -> xcat update, layer1 -> d_out
        k_gates<<<dim3(64, 8), dim3(256), 0, stream>>>(
            girz, gin, ghb, xcat, tbuf,
            (l == 1) ? (float*)d_out : (float*)nullptr, (l == 0) ? 1 : 0);
    }
}

// Round 3
// 316.246 us; speedup vs baseline: 1.0815x; 1.0496x over previous
//
#include <hip/hip_runtime.h>
#include <math.h>

// Problem constants (fixed by the reference)
#define N_NODES 1024
#define BATCH   8
#define FEAT    128        // F == O
#define NDIR    3
#define NB      (N_NODES*BATCH)   // 8192
#define G3      384               // 3*O

typedef __bf16 bf16_t;
using bf16x8 = __attribute__((ext_vector_type(8))) __bf16;
using bf16x4 = __attribute__((ext_vector_type(4))) __bf16;
using f32x4  = __attribute__((ext_vector_type(4))) float;

// async global->LDS 16B per lane; LDS dest must be wave-uniform base (+lane*16)
#define GLOAD_LDS16(g, l) \
    __builtin_amdgcn_global_load_lds((const __attribute__((address_space(1))) void*)(g), \
                                     (__attribute__((address_space(3))) void*)(l), 16, 0, 0)

// ---------------------------------------------------------------------------
// Tiled MFMA GEMM helpers, 4 waves as 2x2 (wr=w>>1, wc=w&1).
// LDS tiles are [R rows][64 k] bf16 (128 B rows) with an XOR-swizzle on the
// 16B slot index: content of (row, slot) = global (row, slot ^ (row&7)).
// global_load_lds writes linearly, so the swizzle is applied by permuting the
// per-lane GLOBAL source address (both-sides-or-neither rule).
// ---------------------------------------------------------------------------
template<int R>
__device__ __forceinline__ void stage_swz(const bf16_t* __restrict__ src, int stride,
                                          int k0, bf16_t* lds, int w, int lane)
{
    #pragma unroll
    for (int q = 0; q < R/32; ++q) {
        int rbase = w*(R/4) + q*8;                 // wave-uniform
        int row = rbase + (lane >> 3);
        int seg = (lane & 7) ^ (row & 7);          // pre-swizzled source slot
        GLOAD_LDS16(src + (size_t)row*stride + k0 + seg*8,
                    (char*)lds + (size_t)rbase*128);
    }
}

// fp32 A-operand stage (k_agg, both layers): load adj fp32, center to bf16,
// ds_write into the swizzled slot. No global round-trip.
__device__ __forceinline__ void stageA_f32(const float* __restrict__ src, int k0,
                                           bf16_t* lds, int w, int lane)
{
    #pragma unroll
    for (int q = 0; q < 2; ++q) {
        int rbase = w*16 + q*8;
        int row = rbase + (lane >> 3);
        int s   = lane & 7;                        // LDS slot this lane fills
        int seg = s ^ (row & 7);                   // source slot for that content
        const float* g = src + (size_t)row*1024 + k0 + seg*8;
        float4 v0 = *reinterpret_cast<const float4*>(g);
        float4 v1 = *reinterpret_cast<const float4*>(g + 4);
        bf16x8 pk;
        pk[0]=(bf16_t)(v0.x-0.5f); pk[1]=(bf16_t)(v0.y-0.5f);
        pk[2]=(bf16_t)(v0.z-0.5f); pk[3]=(bf16_t)(v0.w-0.5f);
        pk[4]=(bf16_t)(v1.x-0.5f); pk[5]=(bf16_t)(v1.y-0.5f);
        pk[6]=(bf16_t)(v1.z-0.5f); pk[7]=(bf16_t)(v1.w-0.5f);
        *reinterpret_cast<bf16x8*>(&lds[row*64 + s*8]) = pk;   // swizzled slot
    }
}

// mfma over one 64-k chunk, reading swizzled LDS.
template<int MI, int NJ>
__device__ __forceinline__ void mfma_swz(const bf16_t* As, const bf16_t* Bs,
                                         f32x4 (&acc)[MI][NJ], int wr, int wc, int lane)
{
    #pragma unroll
    for (int ks = 0; ks < 64; ks += 32) {
        int bslot = ks/8 + (lane >> 4);            // linear slot pre-XOR
        int sx = bslot ^ (lane & 7);               // row&7 == lane&7 for all frags
        bf16x8 af[MI], bfv[NJ];
        #pragma unroll
        for (int i = 0; i < MI; ++i) {
            int row = wr*MI*16 + i*16 + (lane & 15);
            af[i] = *reinterpret_cast<const bf16x8*>(&As[row*64 + sx*8]);
        }
        #pragma unroll
        for (int j = 0; j < NJ; ++j) {
            int row = wc*NJ*16 + j*16 + (lane & 15);
            bfv[j] = *reinterpret_cast<const bf16x8*>(&Bs[row*64 + sx*8]);
        }
        #pragma unroll
        for (int i = 0; i < MI; ++i) {
            #pragma unroll
            for (int j = 0; j < NJ; ++j)
                acc[i][j] = __builtin_amdgcn_mfma_f32_16x16x32_bf16(af[i], bfv[j], acc[i][j], 0, 0, 0);
        }
    }
}

// fast transcendentals via hardware v_exp_f32 (2^x). Error ~1 ulp-class,
// negligible against the 0.25 absmax from adj bf16 quantization.
__device__ __forceinline__ float fast_sigmoid(float x)
{
    float t = __builtin_amdgcn_exp2f(-1.442695041f * x);   // e^-x
    return __builtin_amdgcn_rcpf(1.0f + t);
}
__device__ __forceinline__ float fast_tanh(float x)
{
    float ax = fabsf(x);
    float t = __builtin_amdgcn_exp2f(-2.885390082f * ax);  // e^-2|x|
    float r = (1.0f - t) * __builtin_amdgcn_rcpf(1.0f + t);
    return copysignf(r, x);
}

// ---------------------------------------------------------------------------
// Weight prep, hi/lo split concats (K'=384):
//  m<384: W -> wsup rows 0-383 (pattern A [hi|lo|hi])
//  m in [384,512): Wh -> wsup rows 384-511 (A)
//  m in [512,896): Whh -> wsup rows 512-895 (A)   [merged k_gh weights]
//  m in [896,1280): Wih -> wihc (B [hi|hi|lo])
// ---------------------------------------------------------------------------
__global__ __launch_bounds__(128) void k_wprep(
    const float* __restrict__ W, const float* __restrict__ Wh,
    const float* __restrict__ Whh, const float* __restrict__ Wih,
    bf16_t* __restrict__ wsup,    // [2][896][384]
    bf16_t* __restrict__ wihc)    // [2][384][384]
{
    int m = blockIdx.x, l = blockIdx.y, k = threadIdx.x;
    float w;
    bf16_t* dst;
    bool patB = false;
    if (m < 384) {
        int d = m >> 7, o = m & 127;
        w = W[((size_t)(l*3 + d)*128 + k)*128 + o];
        dst = wsup + ((size_t)l*896 + m)*384;
    } else if (m < 512) {
        int o = m - 384;
        w = Wh[((size_t)l*128 + k)*128 + o];
        dst = wsup + ((size_t)l*896 + m)*384;
    } else if (m < 896) {
        int c = m - 512;
        w = Whh[((size_t)l*384 + c)*128 + k];
        dst = wsup + ((size_t)l*896 + m)*384;
    } else {
        int c = m - 896;
        w = Wih[((size_t)l*384 + c)*128 + k];
        dst = wihc + ((size_t)l*384 + c)*384;
        patB = true;
    }
    bf16_t hi = (bf16_t)w;
    bf16_t lo = (bf16_t)(w - (float)hi);
    if (patB) { dst[k] = hi; dst[128 + k] = hi; dst[256 + k] = lo; }
    else      { dst[k] = hi; dst[128 + k] = lo; dst[256 + k] = hi; }
}

// ---------------------------------------------------------------------------
// x-cat build + colsum zeroing: inputs fp32 [N,B,128] -> xcat [hi|hi|lo]
// ---------------------------------------------------------------------------
__global__ __launch_bounds__(256) void k_xcat(
    const float* __restrict__ X, bf16_t* __restrict__ xcat,
    float* __restrict__ colsum2)       // [2][3072], zeroed here
{
    int idx = blockIdx.x * 256 + threadIdx.x;   // over 8192*128
    if (idx < 2*3072) colsum2[idx] = 0.0f;
    int k = idx & 127, r = idx >> 7;
    int n = r >> 3, b = r & 7;
    float v = X[idx];
    bf16_t hi = (bf16_t)v;
    bf16_t lo = (bf16_t)(v - (float)hi);
    bf16_t* dst = xcat + ((size_t)(b*1024 + n))*384 + k;
    dst[0] = hi; dst[128] = hi; dst[256] = lo;
}

// ---------------------------------------------------------------------------
// k_sup2 (128x128 tiles, 2-phase dbuf): C[m][n] = sum_k' wcat[m][k']*xcat[b][n][k']
//  m<384 : supt (+ fused colsum partials, rounded values, atomicAdd)
//  m in [384,512): tbuf (relu); m>=512: ghb (merged k_gh)
// grid (8 n-tiles, 7 m-tiles, 8 b)
// ---------------------------------------------------------------------------
__global__ __launch_bounds__(256, 2) void k_sup2(
    const bf16_t* __restrict__ Wcat,  // [896][384] (layer slice)
    const bf16_t* __restrict__ xcat,  // [8][1024][384]
    const float* __restrict__ Bcl,    // [3,128]
    const float* __restrict__ Bhl,    // [128]
    const float* __restrict__ bhhl,   // [384]
    bf16_t* __restrict__ supt,        // [24][128][1024]
    float* __restrict__ tbuf,         // [8][128][1024]
    bf16_t* __restrict__ ghb,         // [8192][384]
    float* __restrict__ colsum)       // [3072] (this layer's buffer)
{
    __shared__ bf16_t As[2][128*64];
    __shared__ bf16_t Bs[2][128*64];
    const int t = threadIdx.x, lane = t & 63, w = t >> 6;
    const int wr = w >> 1, wc = w & 1;
    const int n0 = blockIdx.x * 128;
    const int m0 = blockIdx.y * 128;
    const int b  = blockIdx.z;
    const bf16_t* Arow = Wcat + (size_t)m0 * 384;
    const bf16_t* Brow = xcat + ((size_t)b * 1024 + n0) * 384;

    f32x4 acc[4][4] = {};
    stage_swz<128>(Arow, 384, 0, As[0], w, lane);
    stage_swz<128>(Brow, 384, 0, Bs[0], w, lane);
    __syncthreads();
    #pragma unroll
    for (int kt = 0; kt < 6; ++kt) {
        if (kt + 1 < 6) {
            stage_swz<128>(Arow, 384, (kt+1)*64, As[(kt+1)&1], w, lane);
            stage_swz<128>(Brow, 384, (kt+1)*64, Bs[(kt+1)&1], w, lane);
        }
        mfma_swz<4,4>(As[kt&1], Bs[kt&1], acc, wr, wc, lane);
        __syncthreads();
    }
    #pragma unroll
    for (int i = 0; i < 4; ++i) {
        int mb = m0 + wr*64 + i*16 + ((lane >> 4) * 4);
        if (mb < 384) {
            #pragma unroll
            for (int rg = 0; rg < 4; ++rg) {
                int m = mb + rg;
                int d = m >> 7, o = m & 127;
                float bv = Bcl[d*128 + o];
                float psum = 0.0f;
                #pragma unroll
                for (int j = 0; j < 4; ++j) {
                    int n = n0 + wc*64 + j*16 + (lane & 15);
                    bf16_t sv = (bf16_t)(acc[i][j][rg] + bv);
                    supt[((size_t)((d*8 + b)*128 + o))*1024 + n] = sv;
                    psum += (float)sv;   // colsum over the ROUNDED values
                }
                // reduce over lane&15 (the 16 n-owners of this row in this wave)
                psum += __shfl_xor(psum, 1, 64);
                psum += __shfl_xor(psum, 2, 64);
                psum += __shfl_xor(psum, 4, 64);
                psum += __shfl_xor(psum, 8, 64);
                if ((lane & 15) == 0)
                    atomicAdd(&colsum[(d*8 + b)*128 + o], psum);
            }
        } else if (mb < 512) {
            #pragma unroll
            for (int j = 0; j < 4; ++j) {
                int n = n0 + wc*64 + j*16 + (lane & 15);
                #pragma unroll
                for (int rg = 0; rg < 4; ++rg) {
                    int o = mb + rg - 384;
                    tbuf[((size_t)(b*128 + o))*1024 + n] =
                        fmaxf(acc[i][j][rg] + Bhl[o], 0.0f);
                }
            }
        } else {
            #pragma unroll
            for (int j = 0; j < 4; ++j) {
                int n = n0 + wc*64 + j*16 + (lane & 15);
                int c = mb - 512;
                bf16x4 pk;
                #pragma unroll
                for (int rg = 0; rg < 4; ++rg)
                    pk[rg] = (bf16_t)(acc[i][j][rg] + bhhl[c + rg]);
                *reinterpret_cast<bf16x4*>(&ghb[((size_t)(b*1024 + n))*384 + c]) = pk;
            }
        }
    }
}

// ---------------------------------------------------------------------------
// k_agg (64x128 tiles, 2-phase dbuf, adj fp32 staged directly both layers):
//   agg[z][m][o] = sum_n (adj[z][m][n]-0.5)*supt[z][o][n] + 0.5*colsum
// Output aggcat [24576][384] = [hi|lo|hi]. grid (16 m-tiles, 24 z), 3 blk/CU.
// ---------------------------------------------------------------------------
__global__ __launch_bounds__(256, 3) void k_agg(
    const float* __restrict__ adjf,    // [24][1024][1024] fp32
    const bf16_t* __restrict__ supt,   // [24][128][1024]
    const float* __restrict__ colsum,  // [24][128]
    bf16_t* __restrict__ aggcat)       // [24576][384]
{
    __shared__ bf16_t As[2][64*64];
    __shared__ bf16_t Bs[2][128*64];
    const int t = threadIdx.x, lane = t & 63, w = t >> 6;
    const int wr = w >> 1, wc = w & 1;
    const int m0 = blockIdx.x * 64;
    const int z  = blockIdx.y;
    const float*  Af = adjf + (size_t)z * 1024 * 1024 + (size_t)m0 * 1024;
    const bf16_t* Brow = supt + (size_t)z * 128 * 1024;

    f32x4 acc[2][4] = {};
    stageA_f32(Af, 0, As[0], w, lane);
    stage_swz<128>(Brow, 1024, 0, Bs[0], w, lane);
    __syncthreads();
    #pragma unroll
    for (int kt = 0; kt < 16; ++kt) {
        if (kt + 1 < 16) {
            stageA_f32(Af, (kt+1)*64, As[(kt+1)&1], w, lane);
            stage_swz<128>(Brow, 1024, (kt+1)*64, Bs[(kt+1)&1], w, lane);
        }
        mfma_swz<2,4>(As[kt&1], Bs[kt&1], acc, wr, wc, lane);
        __syncthreads();
    }
    #pragma unroll
    for (int i = 0; i < 2; ++i) {
        #pragma unroll
        for (int rg = 0; rg < 4; ++rg) {
            size_t m = (size_t)z*1024 + m0 + wr*32 + i*16 + ((lane >> 4) * 4) + rg;
            bf16_t* row = aggcat + m*384;
            #pragma unroll
            for (int j = 0; j < 4; ++j) {
                int o = wc*64 + j*16 + (lane & 15);
                float v = acc[i][j][rg] + 0.5f * colsum[z*128 + o];
                bf16_t hi = (bf16_t)v;
                bf16_t lo = (bf16_t)(v - (float)hi);
                row[o] = hi; row[128 + o] = lo; row[256 + o] = hi;
            }
        }
    }
}

// ---------------------------------------------------------------------------
// k_gi (128x128 tiles, 2-phase dbuf): gi[m][c] = sum_k' aggcat[m][k']*wihc[c][k']
// c<256 -> girz bf16; c>=256 -> gin fp32. grid (192 m-tiles, 3 c-tiles).
// ---------------------------------------------------------------------------
__global__ __launch_bounds__(256, 2) void k_gi(
    const bf16_t* __restrict__ A,      // [24576][384]
    const bf16_t* __restrict__ B,      // [384][384]
    const float*  __restrict__ bias,   // [384]
    bf16_t* __restrict__ girz,         // [24576][256]
    float* __restrict__ gin)           // [24576][128]
{
    __shared__ bf16_t As[2][128*64];
    __shared__ bf16_t Bs[2][128*64];
    const int t = threadIdx.x, lane = t & 63, w = t >> 6;
    const int wr = w >> 1, wc = w & 1;
    const int m0 = blockIdx.x * 128;
    const int c0 = blockIdx.y * 128;
    const bf16_t* Arow = A + (size_t)m0 * 384;
    const bf16_t* Brow = B + (size_t)c0 * 384;

    f32x4 acc[4][4] = {};
    stage_swz<128>(Arow, 384, 0, As[0], w, lane);
    stage_swz<128>(Brow, 384, 0, Bs[0], w, lane);
    __syncthreads();
    #pragma unroll
    for (int kt = 0; kt < 6; ++kt) {
        if (kt + 1 < 6) {
            stage_swz<128>(Arow, 384, (kt+1)*64, As[(kt+1)&1], w, lane);
            stage_swz<128>(Brow, 384, (kt+1)*64, Bs[(kt+1)&1], w, lane);
        }
        mfma_swz<4,4>(As[kt&1], Bs[kt&1], acc, wr, wc, lane);
        __syncthreads();
    }
    #pragma unroll
    for (int j = 0; j < 4; ++j) {
        int c = c0 + wc*64 + j*16 + (lane & 15);
        float bv = bias[c];
        #pragma unroll
        for (int i = 0; i < 4; ++i) {
            #pragma unroll
            for (int rg = 0; rg < 4; ++rg) {
                int m = m0 + wr*64 + i*16 + ((lane >> 4) * 4) + rg;
                float v = acc[i][j][rg] + bv;
                if (c < 256) girz[(size_t)m*256 + c] = (bf16_t)v;
                else         gin[(size_t)m*128 + (c - 256)] = v;
            }
        }
    }
}

// ---------------------------------------------------------------------------
// GRU gates + sum over d + relu + highway blend.
// h reconstructed exactly from xcat (hi+lo). grid (64 n-blocks of 16, 8 b).
// ---------------------------------------------------------------------------
__global__ __launch_bounds__(256) void k_gates(
    const bf16_t* __restrict__ girz, const float* __restrict__ gin,
    const bf16_t* __restrict__ ghb,
    bf16_t* xcat,                       // NOT restrict: read+write same buffer
    const float* __restrict__ tbuf,
    float* __restrict__ Xout, int write_xcat)
{
    __shared__ float ts[128*17];
    const int b = blockIdx.y, n0 = blockIdx.x * 16;
    const int tid = threadIdx.x;
    {
        int o = tid >> 1, nh = (tid & 1) * 8;
        const float* src = tbuf + ((size_t)(b*128 + o))*1024 + n0 + nh;
        float4 v0 = *reinterpret_cast<const float4*>(src);
        float4 v1 = *reinterpret_cast<const float4*>(src + 4);
        float* dst = &ts[o*17 + nh];
        dst[0]=v0.x; dst[1]=v0.y; dst[2]=v0.z; dst[3]=v0.w;
        dst[4]=v1.x; dst[5]=v1.y; dst[6]=v1.z; dst[7]=v1.w;
    }
    __syncthreads();
    #pragma unroll
    for (int p = 0; p < 8; ++p) {
        int e = p*256 + tid;
        int nn = e >> 7, o = e & 127;
        int n = n0 + nn;
        size_t rb = (size_t)(b*1024 + n);
        bf16_t* xr = xcat + rb*384;
        float h = (float)xr[o] + (float)xr[256 + o];
        const bf16_t* ghr = ghb + rb*G3;
        float g_r = (float)ghr[o], g_z = (float)ghr[128+o], g_n = (float)ghr[256+o];
        float acc = 0.0f;
        #pragma unroll
        for (int d = 0; d < 3; ++d) {
            size_t rr = (size_t)((d*8 + b)*1024 + n);
            float i_r = (float)girz[rr*256 + o];
            float i_z = (float)girz[rr*256 + 128 + o];
            float i_n = gin[rr*128 + o];
            float rg = fast_sigmoid(i_r + g_r);
            float zg = fast_sigmoid(i_z + g_z);
            float ng = fast_tanh(i_n + rg * g_n);
            acc += (1.0f - zg) * ng + zg * h;
        }
        float outv = fmaxf(acc, 0.0f);
        float tg = ts[o*17 + nn];
        float res = outv * tg + h * (1.0f - tg);
        if (Xout) Xout[(size_t)(n*8 + b)*128 + o] = res;
        if (write_xcat) {
            bf16_t hi = (bf16_t)res;
            bf16_t lo = (bf16_t)(res - (float)hi);
            xr[o] = hi; xr[128 + o] = hi; xr[256 + o] = lo;
        }
    }
}

// ---------------------------------------------------------------------------
extern "C" void kernel_launch(void* const* d_in, const int* in_sizes, int n_in,
                              void* d_out, int out_size, void* d_ws, size_t ws_size,
                              hipStream_t stream) {
    const float* inputs = (const float*)d_in[0];   // [1024,8,128]
    const float* adj    = (const float*)d_in[1];   // [3,8,1024,1024]
    const float* W      = (const float*)d_in[2];   // [2,3,128,128]
    const float* Bc     = (const float*)d_in[3];   // [2,3,128]
    const float* Wh     = (const float*)d_in[4];   // [2,128,128]
    const float* Bh     = (const float*)d_in[5];   // [2,128]
    const float* Wih    = (const float*)d_in[6];   // [2,384,128]
    const float* Whh    = (const float*)d_in[7];   // [2,384,128]
    const float* bih    = (const float*)d_in[8];   // [2,384]
    const float* bhh    = (const float*)d_in[9];   // [2,384]

    char* ws = (char*)d_ws;
    float*  tbuf   = (float*)ws;   ws += (size_t)8*128*1024*4;      // 4.19 MB
    bf16_t* xcat   = (bf16_t*)ws;  ws += (size_t)8*1024*384*2;      // 6.29 MB
    bf16_t* ghb    = (bf16_t*)ws;  ws += (size_t)NB*G3*2;           // 6.29 MB
    bf16_t* supt   = (bf16_t*)ws;  ws += (size_t)24*128*1024*2;     // 6.29 MB
    bf16_t* aggcat = (bf16_t*)ws;  ws += (size_t)3*NB*384*2;        // 18.87 MB
    bf16_t* girz   = (bf16_t*)ws;  ws += (size_t)3*NB*256*2;        // 12.58 MB
    float*  gin    = (float*)ws;   ws += (size_t)3*NB*128*4;        // 12.58 MB
    float*  colsum2= (float*)ws;   ws += (size_t)2*24*128*4;        // 24 KB
    bf16_t* wsup   = (bf16_t*)ws;  ws += (size_t)2*896*384*2;       // 1.38 MB
    bf16_t* wihc   = (bf16_t*)ws;                                   // 1.18 MB

    // one-time preps (adj conversion fused into k_agg; colsum zeroed in k_xcat)
    k_wprep<<<dim3(1280, 2), dim3(128), 0, stream>>>(W, Wh, Whh, Wih, wsup, wihc);
    k_xcat<<<dim3(4096), dim3(256), 0, stream>>>(inputs, xcat, colsum2);

    for (int l = 0; l < 2; ++l) {
        float* colsum = colsum2 + l*3072;
        // support (bf16 [z][o][n]) + highway t + gh (merged) + colsum (fused)
        k_sup2<<<dim3(8, 7, 8), dim3(256), 0, stream>>>(
            wsup + (size_t)l*896*384, xcat, Bc + l*3*128, Bh + l*128, bhh + l*G3,
            supt, tbuf, ghb, colsum);
        // agg = (adj-0.5) @ support + 0.5*colsum, adj fp32 staged directly
        k_agg<<<dim3(16, 24), dim3(256), 0, stream>>>(adj, supt, colsum, aggcat);
        // gi = agg @ Wih^T + bih (K'=384)
        k_gi<<<dim3(192, 3), dim3(256), 0, stream>>>(
            aggcat, wihc + (size_t)l*384*384, bih + l*G3, girz, gin);
        // gates + sum_d + relu + highway; layer0 -> xcat update, layer1 -> d_out
        k_gates<<<dim3(64, 8), dim3(256), 0, stream>>>(
            girz, gin, ghb, xcat, tbuf,
            (l == 1) ? (float*)d_out : (float*)nullptr, (l == 0) ? 1 : 0);
    }
}

// Round 4
// 294.481 us; speedup vs baseline: 1.1615x; 1.0739x over previous
//
#include <hip/hip_runtime.h>
#include <math.h>

// Problem constants (fixed by the reference)
#define N_NODES 1024
#define BATCH   8
#define FEAT    128        // F == O
#define NDIR    3
#define NB      (N_NODES*BATCH)   // 8192
#define G3      384               // 3*O

typedef __bf16 bf16_t;
using bf16x8 = __attribute__((ext_vector_type(8))) __bf16;
using bf16x4 = __attribute__((ext_vector_type(4))) __bf16;
using f32x4  = __attribute__((ext_vector_type(4))) float;

// async global->LDS 16B per lane; LDS dest must be wave-uniform base (+lane*16)
#define GLOAD_LDS16(g, l) \
    __builtin_amdgcn_global_load_lds((const __attribute__((address_space(1))) void*)(g), \
                                     (__attribute__((address_space(3))) void*)(l), 16, 0, 0)

// ---------------------------------------------------------------------------
// Tiled MFMA GEMM helpers, 4 waves as 2x2 (wr=w>>1, wc=w&1).
// LDS tiles are [R rows][64 k] bf16 (128 B rows) with an XOR-swizzle on the
// 16B slot index: content of (row, slot) = global (row, slot ^ (row&7)).
// global_load_lds writes linearly, so the swizzle is applied by permuting the
// per-lane GLOBAL source address (both-sides-or-neither rule).
// ---------------------------------------------------------------------------
template<int R>
__device__ __forceinline__ void stage_swz(const bf16_t* __restrict__ src, int stride,
                                          int k0, bf16_t* lds, int w, int lane)
{
    #pragma unroll
    for (int q = 0; q < R/32; ++q) {
        int rbase = w*(R/4) + q*8;                 // wave-uniform
        int row = rbase + (lane >> 3);
        int seg = (lane & 7) ^ (row & 7);          // pre-swizzled source slot
        GLOAD_LDS16(src + (size_t)row*stride + k0 + seg*8,
                    (char*)lds + (size_t)rbase*128);
    }
}

// fp32 A-operand stage (k_aggi, both layers): load adj fp32, center to bf16,
// ds_write into the swizzled slot. No global round-trip.
__device__ __forceinline__ void stageA_f32(const float* __restrict__ src, int k0,
                                           bf16_t* lds, int w, int lane)
{
    #pragma unroll
    for (int q = 0; q < 2; ++q) {
        int rbase = w*16 + q*8;
        int row = rbase + (lane >> 3);
        int s   = lane & 7;                        // LDS slot this lane fills
        int seg = s ^ (row & 7);                   // source slot for that content
        const float* g = src + (size_t)row*1024 + k0 + seg*8;
        float4 v0 = *reinterpret_cast<const float4*>(g);
        float4 v1 = *reinterpret_cast<const float4*>(g + 4);
        bf16x8 pk;
        pk[0]=(bf16_t)(v0.x-0.5f); pk[1]=(bf16_t)(v0.y-0.5f);
        pk[2]=(bf16_t)(v0.z-0.5f); pk[3]=(bf16_t)(v0.w-0.5f);
        pk[4]=(bf16_t)(v1.x-0.5f); pk[5]=(bf16_t)(v1.y-0.5f);
        pk[6]=(bf16_t)(v1.z-0.5f); pk[7]=(bf16_t)(v1.w-0.5f);
        *reinterpret_cast<bf16x8*>(&lds[row*64 + s*8]) = pk;   // swizzled slot
    }
}

// mfma over one 64-k chunk, reading swizzled LDS.
template<int MI, int NJ>
__device__ __forceinline__ void mfma_swz(const bf16_t* As, const bf16_t* Bs,
                                         f32x4 (&acc)[MI][NJ], int wr, int wc, int lane)
{
    #pragma unroll
    for (int ks = 0; ks < 64; ks += 32) {
        int bslot = ks/8 + (lane >> 4);            // linear slot pre-XOR
        int sx = bslot ^ (lane & 7);               // row&7 == lane&7 for all frags
        bf16x8 af[MI], bfv[NJ];
        #pragma unroll
        for (int i = 0; i < MI; ++i) {
            int row = wr*MI*16 + i*16 + (lane & 15);
            af[i] = *reinterpret_cast<const bf16x8*>(&As[row*64 + sx*8]);
        }
        #pragma unroll
        for (int j = 0; j < NJ; ++j) {
            int row = wc*NJ*16 + j*16 + (lane & 15);
            bfv[j] = *reinterpret_cast<const bf16x8*>(&Bs[row*64 + sx*8]);
        }
        #pragma unroll
        for (int i = 0; i < MI; ++i) {
            #pragma unroll
            for (int j = 0; j < NJ; ++j)
                acc[i][j] = __builtin_amdgcn_mfma_f32_16x16x32_bf16(af[i], bfv[j], acc[i][j], 0, 0, 0);
        }
    }
}

// fast transcendentals via hardware v_exp_f32 (2^x). Error ~1 ulp-class,
// negligible against the 0.25 absmax from adj bf16 quantization.
__device__ __forceinline__ float fast_sigmoid(float x)
{
    float t = __builtin_amdgcn_exp2f(-1.442695041f * x);   // e^-x
    return __builtin_amdgcn_rcpf(1.0f + t);
}
__device__ __forceinline__ float fast_tanh(float x)
{
    float ax = fabsf(x);
    float t = __builtin_amdgcn_exp2f(-2.885390082f * ax);  // e^-2|x|
    float r = (1.0f - t) * __builtin_amdgcn_rcpf(1.0f + t);
    return copysignf(r, x);
}

// ---------------------------------------------------------------------------
// Weight prep, hi/lo split concats (K'=384):
//  m<384: W -> wsup rows 0-383 (pattern A [hi|lo|hi])
//  m in [384,512): Wh -> wsup rows 384-511 (A)
//  m in [512,896): Whh -> wsup rows 512-895 (A)   [merged k_gh weights]
//  m in [896,1280): Wih -> wihc (B [hi|hi|lo])
// ---------------------------------------------------------------------------
__global__ __launch_bounds__(128) void k_wprep(
    const float* __restrict__ W, const float* __restrict__ Wh,
    const float* __restrict__ Whh, const float* __restrict__ Wih,
    bf16_t* __restrict__ wsup,    // [2][896][384]
    bf16_t* __restrict__ wihc)    // [2][384][384]
{
    int m = blockIdx.x, l = blockIdx.y, k = threadIdx.x;
    float w;
    bf16_t* dst;
    bool patB = false;
    if (m < 384) {
        int d = m >> 7, o = m & 127;
        w = W[((size_t)(l*3 + d)*128 + k)*128 + o];
        dst = wsup + ((size_t)l*896 + m)*384;
    } else if (m < 512) {
        int o = m - 384;
        w = Wh[((size_t)l*128 + k)*128 + o];
        dst = wsup + ((size_t)l*896 + m)*384;
    } else if (m < 896) {
        int c = m - 512;
        w = Whh[((size_t)l*384 + c)*128 + k];
        dst = wsup + ((size_t)l*896 + m)*384;
    } else {
        int c = m - 896;
        w = Wih[((size_t)l*384 + c)*128 + k];
        dst = wihc + ((size_t)l*384 + c)*384;
        patB = true;
    }
    bf16_t hi = (bf16_t)w;
    bf16_t lo = (bf16_t)(w - (float)hi);
    if (patB) { dst[k] = hi; dst[128 + k] = hi; dst[256 + k] = lo; }
    else      { dst[k] = hi; dst[128 + k] = lo; dst[256 + k] = hi; }
}

// ---------------------------------------------------------------------------
// x-cat build + colsum zeroing: inputs fp32 [N,B,128] -> xcat [hi|hi|lo]
// ---------------------------------------------------------------------------
__global__ __launch_bounds__(256) void k_xcat(
    const float* __restrict__ X, bf16_t* __restrict__ xcat,
    float* __restrict__ colsum2)       // [2][3072], zeroed here
{
    int idx = blockIdx.x * 256 + threadIdx.x;   // over 8192*128
    if (idx < 2*3072) colsum2[idx] = 0.0f;
    int k = idx & 127, r = idx >> 7;
    int n = r >> 3, b = r & 7;
    float v = X[idx];
    bf16_t hi = (bf16_t)v;
    bf16_t lo = (bf16_t)(v - (float)hi);
    bf16_t* dst = xcat + ((size_t)(b*1024 + n))*384 + k;
    dst[0] = hi; dst[128] = hi; dst[256] = lo;
}

// ---------------------------------------------------------------------------
// k_sup2 (128x128 tiles, 2-phase dbuf): C[m][n] = sum_k' wcat[m][k']*xcat[b][n][k']
//  m<384 : supt (+ fused colsum partials, rounded values, atomicAdd)
//  m in [384,512): tbuf (relu); m>=512: ghb (merged k_gh)
// grid (8 n-tiles, 7 m-tiles, 8 b)
// ---------------------------------------------------------------------------
__global__ __launch_bounds__(256, 2) void k_sup2(
    const bf16_t* __restrict__ Wcat,  // [896][384] (layer slice)
    const bf16_t* __restrict__ xcat,  // [8][1024][384]
    const float* __restrict__ Bcl,    // [3,128]
    const float* __restrict__ Bhl,    // [128]
    const float* __restrict__ bhhl,   // [384]
    bf16_t* __restrict__ supt,        // [24][128][1024]
    float* __restrict__ tbuf,         // [8][128][1024]
    bf16_t* __restrict__ ghb,         // [8192][384]
    float* __restrict__ colsum)       // [3072] (this layer's buffer)
{
    __shared__ bf16_t As[2][128*64];
    __shared__ bf16_t Bs[2][128*64];
    const int t = threadIdx.x, lane = t & 63, w = t >> 6;
    const int wr = w >> 1, wc = w & 1;
    const int n0 = blockIdx.x * 128;
    const int m0 = blockIdx.y * 128;
    const int b  = blockIdx.z;
    const bf16_t* Arow = Wcat + (size_t)m0 * 384;
    const bf16_t* Brow = xcat + ((size_t)b * 1024 + n0) * 384;

    f32x4 acc[4][4] = {};
    stage_swz<128>(Arow, 384, 0, As[0], w, lane);
    stage_swz<128>(Brow, 384, 0, Bs[0], w, lane);
    __syncthreads();
    #pragma unroll
    for (int kt = 0; kt < 6; ++kt) {
        if (kt + 1 < 6) {
            stage_swz<128>(Arow, 384, (kt+1)*64, As[(kt+1)&1], w, lane);
            stage_swz<128>(Brow, 384, (kt+1)*64, Bs[(kt+1)&1], w, lane);
        }
        mfma_swz<4,4>(As[kt&1], Bs[kt&1], acc, wr, wc, lane);
        __syncthreads();
    }
    #pragma unroll
    for (int i = 0; i < 4; ++i) {
        int mb = m0 + wr*64 + i*16 + ((lane >> 4) * 4);
        if (mb < 384) {
            #pragma unroll
            for (int rg = 0; rg < 4; ++rg) {
                int m = mb + rg;
                int d = m >> 7, o = m & 127;
                float bv = Bcl[d*128 + o];
                float psum = 0.0f;
                #pragma unroll
                for (int j = 0; j < 4; ++j) {
                    int n = n0 + wc*64 + j*16 + (lane & 15);
                    bf16_t sv = (bf16_t)(acc[i][j][rg] + bv);
                    supt[((size_t)((d*8 + b)*128 + o))*1024 + n] = sv;
                    psum += (float)sv;   // colsum over the ROUNDED values
                }
                // reduce over lane&15 (the 16 n-owners of this row in this wave)
                psum += __shfl_xor(psum, 1, 64);
                psum += __shfl_xor(psum, 2, 64);
                psum += __shfl_xor(psum, 4, 64);
                psum += __shfl_xor(psum, 8, 64);
                if ((lane & 15) == 0)
                    atomicAdd(&colsum[(d*8 + b)*128 + o], psum);
            }
        } else if (mb < 512) {
            #pragma unroll
            for (int j = 0; j < 4; ++j) {
                int n = n0 + wc*64 + j*16 + (lane & 15);
                #pragma unroll
                for (int rg = 0; rg < 4; ++rg) {
                    int o = mb + rg - 384;
                    tbuf[((size_t)(b*128 + o))*1024 + n] =
                        fmaxf(acc[i][j][rg] + Bhl[o], 0.0f);
                }
            }
        } else {
            #pragma unroll
            for (int j = 0; j < 4; ++j) {
                int n = n0 + wc*64 + j*16 + (lane & 15);
                int c = mb - 512;
                bf16x4 pk;
                #pragma unroll
                for (int rg = 0; rg < 4; ++rg)
                    pk[rg] = (bf16_t)(acc[i][j][rg] + bhhl[c + rg]);
                *reinterpret_cast<bf16x4*>(&ghb[((size_t)(b*1024 + n))*384 + c]) = pk;
            }
        }
    }
}

// ---------------------------------------------------------------------------
// k_aggi: FUSED agg + gi per 64-node tile.
//   Phase A (agg): agg[z][m][o] = sum_n (adj[z][m][n]-0.5)*supt[z][o][n]
//                  + 0.5*colsum[z][o]     (64x128 tile, 16 K-steps, dbuf)
//   -> hi/lo split into swizzled LDS panel aggls[64][256] (hi k=0..127, lo 128..255)
//   Phase B (gi): gi[m][c] = sum_k' agg_cat[m][k'] * wihc[c][k'] + bih[c]
//                  K'=384 maps to aggls chunks {0,1,2,3,0,1}; W staged dbuf.
//   c<256 -> girz bf16; c>=256 -> gin fp32.
// grid (16 m-tiles, 24 z). LDS = 48K pool + 32K aggls = 80 KB -> 2 blocks/CU.
// ---------------------------------------------------------------------------
__device__ __forceinline__ int aggls_off(int row, int k)
{
    // 16B-slot XOR swizzle: stride 512 B rows would put all rows of a column
    // in one bank group; XOR the slot with row&15 spreads 16 rows -> 2-way.
    return row*256 + (((k >> 3) ^ (row & 15)) << 3) + (k & 7);
}

__global__ __launch_bounds__(256, 2) void k_aggi(
    const float* __restrict__ adjf,    // [24][1024][1024] fp32
    const bf16_t* __restrict__ supt,   // [24][128][1024]
    const float* __restrict__ colsum,  // [24][128]
    const bf16_t* __restrict__ wihcL,  // [384][384] (layer slice, pattern B)
    const float* __restrict__ biasL,   // [384] (bih layer slice)
    bf16_t* __restrict__ girz,         // [24576][256]
    float* __restrict__ gin)           // [24576][128]
{
    __shared__ char pool[49152];               // As 16K + Bs 32K; reused as BsG
    __shared__ bf16_t aggls[64*256];           // 32 KB persistent panel
    bf16_t* As  = (bf16_t*)pool;               // [2][64*64]
    bf16_t* Bs  = (bf16_t*)(pool + 16384);     // [2][128*64]
    bf16_t* BsG = (bf16_t*)pool;               // [2][128*64] (phase B)

    const int t = threadIdx.x, lane = t & 63, w = t >> 6;
    const int wr = w >> 1, wc = w & 1;
    const int m0 = blockIdx.x * 64;
    const int z  = blockIdx.y;
    const float*  Af   = adjf + (size_t)z * 1024 * 1024 + (size_t)m0 * 1024;
    const bf16_t* Brow = supt + (size_t)z * 128 * 1024;

    // ---- Phase A: agg ----
    f32x4 acc[2][4] = {};
    stageA_f32(Af, 0, As, w, lane);
    stage_swz<128>(Brow, 1024, 0, Bs, w, lane);
    __syncthreads();
    #pragma unroll
    for (int kt = 0; kt < 16; ++kt) {
        if (kt + 1 < 16) {
            stageA_f32(Af, (kt+1)*64, As + ((kt+1)&1)*4096, w, lane);
            stage_swz<128>(Brow, 1024, (kt+1)*64, Bs + ((kt+1)&1)*8192, w, lane);
        }
        mfma_swz<2,4>(As + (kt&1)*4096, Bs + (kt&1)*8192, acc, wr, wc, lane);
        __syncthreads();
    }

    // pool is free now: prefetch first gi weight chunk while writing aggls
    stage_swz<128>(wihcL, 384, 0, BsG, w, lane);

    // agg epilogue -> aggls (hi|lo, swizzled slots)
    #pragma unroll
    for (int i = 0; i < 2; ++i) {
        #pragma unroll
        for (int rg = 0; rg < 4; ++rg) {
            int row = wr*32 + i*16 + ((lane >> 4) * 4) + rg;
            #pragma unroll
            for (int j = 0; j < 4; ++j) {
                int o = wc*64 + j*16 + (lane & 15);
                float v = acc[i][j][rg] + 0.5f * colsum[z*128 + o];
                bf16_t hi = (bf16_t)v;
                bf16_t lo = (bf16_t)(v - (float)hi);
                aggls[aggls_off(row, o)]       = hi;
                aggls[aggls_off(row, 128 + o)] = lo;
            }
        }
    }
    __syncthreads();   // aggls visible; BsG[0] staged (vmcnt drained)

    // ---- Phase B: gi over 3 c-chunks of 128 ----
    #pragma unroll
    for (int cc = 0; cc < 3; ++cc) {
        f32x4 a2[2][4] = {};
        #pragma unroll
        for (int kt = 0; kt < 6; ++kt) {
            int it = cc*6 + kt;
            if (it + 1 < 18) {
                int nc = (it+1)/6, nk = (it+1)%6;
                stage_swz<128>(wihcL + (size_t)nc*128*384, 384, nk*64,
                               BsG + ((it+1)&1)*8192, w, lane);
            }
            const bf16_t* Bcur = BsG + (it&1)*8192;
            int akk = (kt < 4 ? kt : kt - 4) * 64;   // A chunks {0,1,2,3,0,1}
            #pragma unroll
            for (int ks = 0; ks < 64; ks += 32) {
                bf16x8 af[2], bfv[4];
                #pragma unroll
                for (int i = 0; i < 2; ++i) {
                    int row = wr*32 + i*16 + (lane & 15);
                    int ss = ((akk + ks)/8 + (lane >> 4)) ^ (lane & 15);
                    af[i] = *reinterpret_cast<const bf16x8*>(&aggls[row*256 + ss*8]);
                }
                #pragma unroll
                for (int j = 0; j < 4; ++j) {
                    int row = wc*64 + j*16 + (lane & 15);
                    int sx = (ks/8 + (lane >> 4)) ^ (lane & 7);
                    bfv[j] = *reinterpret_cast<const bf16x8*>(&Bcur[row*64 + sx*8]);
                }
                #pragma unroll
                for (int i = 0; i < 2; ++i) {
                    #pragma unroll
                    for (int j = 0; j < 4; ++j)
                        a2[i][j] = __builtin_amdgcn_mfma_f32_16x16x32_bf16(af[i], bfv[j], a2[i][j], 0, 0, 0);
                }
            }
            __syncthreads();
        }
        // gi epilogue for this c-chunk (cc uniform: dtype branch is uniform)
        #pragma unroll
        for (int j = 0; j < 4; ++j) {
            int c = cc*128 + wc*64 + j*16 + (lane & 15);
            float bv = biasL[c];
            #pragma unroll
            for (int i = 0; i < 2; ++i) {
                #pragma unroll
                for (int rg = 0; rg < 4; ++rg) {
                    int rloc = wr*32 + i*16 + ((lane >> 4) * 4) + rg;
                    size_t m = (size_t)z*1024 + m0 + rloc;
                    float v = a2[i][j][rg] + bv;
                    if (c < 256) girz[m*256 + c] = (bf16_t)v;
                    else         gin[m*128 + (c - 256)] = v;
                }
            }
        }
    }
}

// ---------------------------------------------------------------------------
// GRU gates + sum over d + relu + highway blend.
// h reconstructed exactly from xcat (hi+lo). grid (64 n-blocks of 16, 8 b).
// ---------------------------------------------------------------------------
__global__ __launch_bounds__(256) void k_gates(
    const bf16_t* __restrict__ girz, const float* __restrict__ gin,
    const bf16_t* __restrict__ ghb,
    bf16_t* xcat,                       // NOT restrict: read+write same buffer
    const float* __restrict__ tbuf,
    float* __restrict__ Xout, int write_xcat)
{
    __shared__ float ts[128*17];
    const int b = blockIdx.y, n0 = blockIdx.x * 16;
    const int tid = threadIdx.x;
    {
        int o = tid >> 1, nh = (tid & 1) * 8;
        const float* src = tbuf + ((size_t)(b*128 + o))*1024 + n0 + nh;
        float4 v0 = *reinterpret_cast<const float4*>(src);
        float4 v1 = *reinterpret_cast<const float4*>(src + 4);
        float* dst = &ts[o*17 + nh];
        dst[0]=v0.x; dst[1]=v0.y; dst[2]=v0.z; dst[3]=v0.w;
        dst[4]=v1.x; dst[5]=v1.y; dst[6]=v1.z; dst[7]=v1.w;
    }
    __syncthreads();
    #pragma unroll
    for (int p = 0; p < 8; ++p) {
        int e = p*256 + tid;
        int nn = e >> 7, o = e & 127;
        int n = n0 + nn;
        size_t rb = (size_t)(b*1024 + n);
        bf16_t* xr = xcat + rb*384;
        float h = (float)xr[o] + (float)xr[256 + o];
        const bf16_t* ghr = ghb + rb*G3;
        float g_r = (float)ghr[o], g_z = (float)ghr[128+o], g_n = (float)ghr[256+o];
        float acc = 0.0f;
        #pragma unroll
        for (int d = 0; d < 3; ++d) {
            size_t rr = (size_t)((d*8 + b)*1024 + n);
            float i_r = (float)girz[rr*256 + o];
            float i_z = (float)girz[rr*256 + 128 + o];
            float i_n = gin[rr*128 + o];
            float rg = fast_sigmoid(i_r + g_r);
            float zg = fast_sigmoid(i_z + g_z);
            float ng = fast_tanh(i_n + rg * g_n);
            acc += (1.0f - zg) * ng + zg * h;
        }
        float outv = fmaxf(acc, 0.0f);
        float tg = ts[o*17 + nn];
        float res = outv * tg + h * (1.0f - tg);
        if (Xout) Xout[(size_t)(n*8 + b)*128 + o] = res;
        if (write_xcat) {
            bf16_t hi = (bf16_t)res;
            bf16_t lo = (bf16_t)(res - (float)hi);
            xr[o] = hi; xr[128 + o] = hi; xr[256 + o] = lo;
        }
    }
}

// ---------------------------------------------------------------------------
extern "C" void kernel_launch(void* const* d_in, const int* in_sizes, int n_in,
                              void* d_out, int out_size, void* d_ws, size_t ws_size,
                              hipStream_t stream) {
    const float* inputs = (const float*)d_in[0];   // [1024,8,128]
    const float* adj    = (const float*)d_in[1];   // [3,8,1024,1024]
    const float* W      = (const float*)d_in[2];   // [2,3,128,128]
    const float* Bc     = (const float*)d_in[3];   // [2,3,128]
    const float* Wh     = (const float*)d_in[4];   // [2,128,128]
    const float* Bh     = (const float*)d_in[5];   // [2,128]
    const float* Wih    = (const float*)d_in[6];   // [2,384,128]
    const float* Whh    = (const float*)d_in[7];   // [2,384,128]
    const float* bih    = (const float*)d_in[8];   // [2,384]
    const float* bhh    = (const float*)d_in[9];   // [2,384]

    char* ws = (char*)d_ws;
    float*  tbuf   = (float*)ws;   ws += (size_t)8*128*1024*4;      // 4.19 MB
    bf16_t* xcat   = (bf16_t*)ws;  ws += (size_t)8*1024*384*2;      // 6.29 MB
    bf16_t* ghb    = (bf16_t*)ws;  ws += (size_t)NB*G3*2;           // 6.29 MB
    bf16_t* supt   = (bf16_t*)ws;  ws += (size_t)24*128*1024*2;     // 6.29 MB
    bf16_t* girz   = (bf16_t*)ws;  ws += (size_t)3*NB*256*2;        // 12.58 MB
    float*  gin    = (float*)ws;   ws += (size_t)3*NB*128*4;        // 12.58 MB
    float*  colsum2= (float*)ws;   ws += (size_t)2*24*128*4;        // 24 KB
    bf16_t* wsup   = (bf16_t*)ws;  ws += (size_t)2*896*384*2;       // 1.38 MB
    bf16_t* wihc   = (bf16_t*)ws;                                   // 1.18 MB

    // one-time preps (adj conversion fused into k_aggi; colsum zeroed in k_xcat)
    k_wprep<<<dim3(1280, 2), dim3(128), 0, stream>>>(W, Wh, Whh, Wih, wsup, wihc);
    k_xcat<<<dim3(4096), dim3(256), 0, stream>>>(inputs, xcat, colsum2);

    for (int l = 0; l < 2; ++l) {
        float* colsum = colsum2 + l*3072;
        // support (bf16 [z][o][n]) + highway t + gh (merged) + colsum (fused)
        k_sup2<<<dim3(8, 7, 8), dim3(256), 0, stream>>>(
            wsup + (size_t)l*896*384, xcat, Bc + l*3*128, Bh + l*128, bhh + l*G3,
            supt, tbuf, ghb, colsum);
        // FUSED: agg = (adj-0.5) @ support + 0.5*colsum ; gi = agg_cat @ Wih^T + bih
        k_aggi<<<dim3(16, 24), dim3(256), 0, stream>>>(
            adj, supt, colsum, wihc + (size_t)l*384*384, bih + l*G3, girz, gin);
        // gates + sum_d + relu + highway; layer0 -> xcat update, layer1 -> d_out
        k_gates<<<dim3(64, 8), dim3(256), 0, stream>>>(
            girz, gin, ghb, xcat, tbuf,
            (l == 1) ? (float*)d_out : (float*)nullptr, (l == 0) ? 1 : 0);
    }
}

// Round 5
// 289.915 us; speedup vs baseline: 1.1797x; 1.0158x over previous
//
#include <hip/hip_runtime.h>
#include <math.h>

// Problem constants (fixed by the reference)
#define N_NODES 1024
#define BATCH   8
#define FEAT    128        // F == O
#define NDIR    3
#define NB      (N_NODES*BATCH)   // 8192
#define G3      384               // 3*O

typedef __bf16 bf16_t;
using bf16x8 = __attribute__((ext_vector_type(8))) __bf16;
using bf16x4 = __attribute__((ext_vector_type(4))) __bf16;
using f32x4  = __attribute__((ext_vector_type(4))) float;

// async global->LDS 16B per lane; LDS dest must be wave-uniform base (+lane*16)
#define GLOAD_LDS16(g, l) \
    __builtin_amdgcn_global_load_lds((const __attribute__((address_space(1))) void*)(g), \
                                     (__attribute__((address_space(3))) void*)(l), 16, 0, 0)

// ---------------------------------------------------------------------------
// Tiled MFMA GEMM helpers, 4 waves as 2x2 (wr=w>>1, wc=w&1).
// LDS tiles are [R rows][64 k] bf16 (128 B rows) with an XOR-swizzle on the
// 16B slot index: content of (row, slot) = global (row, slot ^ (row&7)).
// global_load_lds writes linearly, so the swizzle is applied by permuting the
// per-lane GLOBAL source address (both-sides-or-neither rule).
// ---------------------------------------------------------------------------
template<int R>
__device__ __forceinline__ void stage_swz(const bf16_t* __restrict__ src, int stride,
                                          int k0, bf16_t* lds, int w, int lane)
{
    #pragma unroll
    for (int q = 0; q < R/32; ++q) {
        int rbase = w*(R/4) + q*8;                 // wave-uniform
        int row = rbase + (lane >> 3);
        int seg = (lane & 7) ^ (row & 7);          // pre-swizzled source slot
        GLOAD_LDS16(src + (size_t)row*stride + k0 + seg*8,
                    (char*)lds + (size_t)rbase*128);
    }
}

// T14 async-STAGE split for the adj fp32 A-operand of k_aggi.
// issue: fire global loads into regs (no wait). commit: convert+ds_write
// (placed AFTER the MFMA block so the vmcnt wait is covered by compute).
__device__ __forceinline__ void stageA_issue(const float* __restrict__ src, int k0,
                                             float4 (&r)[4], int w, int lane)
{
    #pragma unroll
    for (int q = 0; q < 2; ++q) {
        int row = w*16 + q*8 + (lane >> 3);
        int seg = (lane & 7) ^ (row & 7);          // source slot for this lane's LDS slot
        const float* g = src + (size_t)row*1024 + k0 + seg*8;
        r[q*2+0] = *reinterpret_cast<const float4*>(g);
        r[q*2+1] = *reinterpret_cast<const float4*>(g + 4);
    }
}

__device__ __forceinline__ void stageA_commit(const float4 (&r)[4], bf16_t* lds,
                                              int w, int lane)
{
    #pragma unroll
    for (int q = 0; q < 2; ++q) {
        int row = w*16 + q*8 + (lane >> 3);
        int s   = lane & 7;                        // LDS slot this lane fills
        float4 v0 = r[q*2+0], v1 = r[q*2+1];
        bf16x8 pk;
        pk[0]=(bf16_t)(v0.x-0.5f); pk[1]=(bf16_t)(v0.y-0.5f);
        pk[2]=(bf16_t)(v0.z-0.5f); pk[3]=(bf16_t)(v0.w-0.5f);
        pk[4]=(bf16_t)(v1.x-0.5f); pk[5]=(bf16_t)(v1.y-0.5f);
        pk[6]=(bf16_t)(v1.z-0.5f); pk[7]=(bf16_t)(v1.w-0.5f);
        *reinterpret_cast<bf16x8*>(&lds[row*64 + s*8]) = pk;   // swizzled slot
    }
}

// mfma over one 64-k chunk, reading swizzled LDS.
template<int MI, int NJ>
__device__ __forceinline__ void mfma_swz(const bf16_t* As, const bf16_t* Bs,
                                         f32x4 (&acc)[MI][NJ], int wr, int wc, int lane)
{
    #pragma unroll
    for (int ks = 0; ks < 64; ks += 32) {
        int bslot = ks/8 + (lane >> 4);            // linear slot pre-XOR
        int sx = bslot ^ (lane & 7);               // row&7 == lane&7 for all frags
        bf16x8 af[MI], bfv[NJ];
        #pragma unroll
        for (int i = 0; i < MI; ++i) {
            int row = wr*MI*16 + i*16 + (lane & 15);
            af[i] = *reinterpret_cast<const bf16x8*>(&As[row*64 + sx*8]);
        }
        #pragma unroll
        for (int j = 0; j < NJ; ++j) {
            int row = wc*NJ*16 + j*16 + (lane & 15);
            bfv[j] = *reinterpret_cast<const bf16x8*>(&Bs[row*64 + sx*8]);
        }
        #pragma unroll
        for (int i = 0; i < MI; ++i) {
            #pragma unroll
            for (int j = 0; j < NJ; ++j)
                acc[i][j] = __builtin_amdgcn_mfma_f32_16x16x32_bf16(af[i], bfv[j], acc[i][j], 0, 0, 0);
        }
    }
}

// fast transcendentals via hardware v_exp_f32 (2^x). Error ~1 ulp-class,
// negligible against the 0.25 absmax from adj bf16 quantization.
__device__ __forceinline__ float fast_sigmoid(float x)
{
    float t = __builtin_amdgcn_exp2f(-1.442695041f * x);   // e^-x
    return __builtin_amdgcn_rcpf(1.0f + t);
}
__device__ __forceinline__ float fast_tanh(float x)
{
    float ax = fabsf(x);
    float t = __builtin_amdgcn_exp2f(-2.885390082f * ax);  // e^-2|x|
    float r = (1.0f - t) * __builtin_amdgcn_rcpf(1.0f + t);
    return copysignf(r, x);
}

// ---------------------------------------------------------------------------
// Weight prep, hi/lo split concats (K'=384):
//  m<384: W -> wsup rows 0-383 (pattern A [hi|lo|hi])
//  m in [384,512): Wh -> wsup rows 384-511 (A)
//  m in [512,896): Whh -> wsup rows 512-895 (A)   [merged k_gh weights]
//  m in [896,1280): Wih -> wihc (B [hi|hi|lo])
// ---------------------------------------------------------------------------
__global__ __launch_bounds__(128) void k_wprep(
    const float* __restrict__ W, const float* __restrict__ Wh,
    const float* __restrict__ Whh, const float* __restrict__ Wih,
    bf16_t* __restrict__ wsup,    // [2][896][384]
    bf16_t* __restrict__ wihc)    // [2][384][384]
{
    int m = blockIdx.x, l = blockIdx.y, k = threadIdx.x;
    float w;
    bf16_t* dst;
    bool patB = false;
    if (m < 384) {
        int d = m >> 7, o = m & 127;
        w = W[((size_t)(l*3 + d)*128 + k)*128 + o];
        dst = wsup + ((size_t)l*896 + m)*384;
    } else if (m < 512) {
        int o = m - 384;
        w = Wh[((size_t)l*128 + k)*128 + o];
        dst = wsup + ((size_t)l*896 + m)*384;
    } else if (m < 896) {
        int c = m - 512;
        w = Whh[((size_t)l*384 + c)*128 + k];
        dst = wsup + ((size_t)l*896 + m)*384;
    } else {
        int c = m - 896;
        w = Wih[((size_t)l*384 + c)*128 + k];
        dst = wihc + ((size_t)l*384 + c)*384;
        patB = true;
    }
    bf16_t hi = (bf16_t)w;
    bf16_t lo = (bf16_t)(w - (float)hi);
    if (patB) { dst[k] = hi; dst[128 + k] = hi; dst[256 + k] = lo; }
    else      { dst[k] = hi; dst[128 + k] = lo; dst[256 + k] = hi; }
}

// ---------------------------------------------------------------------------
// x-cat build + colsum zeroing: inputs fp32 [N,B,128] -> xcat [hi|hi|lo]
// ---------------------------------------------------------------------------
__global__ __launch_bounds__(256) void k_xcat(
    const float* __restrict__ X, bf16_t* __restrict__ xcat,
    float* __restrict__ colsum2)       // [2][3072], zeroed here
{
    int idx = blockIdx.x * 256 + threadIdx.x;   // over 8192*128
    if (idx < 2*3072) colsum2[idx] = 0.0f;
    int k = idx & 127, r = idx >> 7;
    int n = r >> 3, b = r & 7;
    float v = X[idx];
    bf16_t hi = (bf16_t)v;
    bf16_t lo = (bf16_t)(v - (float)hi);
    bf16_t* dst = xcat + ((size_t)(b*1024 + n))*384 + k;
    dst[0] = hi; dst[128] = hi; dst[256] = lo;
}

// ---------------------------------------------------------------------------
// k_sup2 (128x128 tiles, 2-phase dbuf): C[m][n] = sum_k' wcat[m][k']*xcat[b][n][k']
//  m<384 : supt (+ fused colsum partials, rounded values, atomicAdd)
//  m in [384,512): tbuf (relu); m>=512: ghb (merged k_gh)
// grid (8 n-tiles, 7 m-tiles, 8 b)
// ---------------------------------------------------------------------------
__global__ __launch_bounds__(256, 2) void k_sup2(
    const bf16_t* __restrict__ Wcat,  // [896][384] (layer slice)
    const bf16_t* __restrict__ xcat,  // [8][1024][384]
    const float* __restrict__ Bcl,    // [3,128]
    const float* __restrict__ Bhl,    // [128]
    const float* __restrict__ bhhl,   // [384]
    bf16_t* __restrict__ supt,        // [24][128][1024]
    float* __restrict__ tbuf,         // [8][128][1024]
    bf16_t* __restrict__ ghb,         // [8192][384]
    float* __restrict__ colsum)       // [3072] (this layer's buffer)
{
    __shared__ bf16_t As[2][128*64];
    __shared__ bf16_t Bs[2][128*64];
    const int t = threadIdx.x, lane = t & 63, w = t >> 6;
    const int wr = w >> 1, wc = w & 1;
    const int n0 = blockIdx.x * 128;
    const int m0 = blockIdx.y * 128;
    const int b  = blockIdx.z;
    const bf16_t* Arow = Wcat + (size_t)m0 * 384;
    const bf16_t* Brow = xcat + ((size_t)b * 1024 + n0) * 384;

    f32x4 acc[4][4] = {};
    stage_swz<128>(Arow, 384, 0, As[0], w, lane);
    stage_swz<128>(Brow, 384, 0, Bs[0], w, lane);
    __syncthreads();
    #pragma unroll
    for (int kt = 0; kt < 6; ++kt) {
        if (kt + 1 < 6) {
            stage_swz<128>(Arow, 384, (kt+1)*64, As[(kt+1)&1], w, lane);
            stage_swz<128>(Brow, 384, (kt+1)*64, Bs[(kt+1)&1], w, lane);
        }
        mfma_swz<4,4>(As[kt&1], Bs[kt&1], acc, wr, wc, lane);
        __syncthreads();
    }
    #pragma unroll
    for (int i = 0; i < 4; ++i) {
        int mb = m0 + wr*64 + i*16 + ((lane >> 4) * 4);
        if (mb < 384) {
            #pragma unroll
            for (int rg = 0; rg < 4; ++rg) {
                int m = mb + rg;
                int d = m >> 7, o = m & 127;
                float bv = Bcl[d*128 + o];
                float psum = 0.0f;
                #pragma unroll
                for (int j = 0; j < 4; ++j) {
                    int n = n0 + wc*64 + j*16 + (lane & 15);
                    bf16_t sv = (bf16_t)(acc[i][j][rg] + bv);
                    supt[((size_t)((d*8 + b)*128 + o))*1024 + n] = sv;
                    psum += (float)sv;   // colsum over the ROUNDED values
                }
                // reduce over lane&15 (the 16 n-owners of this row in this wave)
                psum += __shfl_xor(psum, 1, 64);
                psum += __shfl_xor(psum, 2, 64);
                psum += __shfl_xor(psum, 4, 64);
                psum += __shfl_xor(psum, 8, 64);
                if ((lane & 15) == 0)
                    atomicAdd(&colsum[(d*8 + b)*128 + o], psum);
            }
        } else if (mb < 512) {
            #pragma unroll
            for (int j = 0; j < 4; ++j) {
                int n = n0 + wc*64 + j*16 + (lane & 15);
                #pragma unroll
                for (int rg = 0; rg < 4; ++rg) {
                    int o = mb + rg - 384;
                    tbuf[((size_t)(b*128 + o))*1024 + n] =
                        fmaxf(acc[i][j][rg] + Bhl[o], 0.0f);
                }
            }
        } else {
            #pragma unroll
            for (int j = 0; j < 4; ++j) {
                int n = n0 + wc*64 + j*16 + (lane & 15);
                int c = mb - 512;
                bf16x4 pk;
                #pragma unroll
                for (int rg = 0; rg < 4; ++rg)
                    pk[rg] = (bf16_t)(acc[i][j][rg] + bhhl[c + rg]);
                *reinterpret_cast<bf16x4*>(&ghb[((size_t)(b*1024 + n))*384 + c]) = pk;
            }
        }
    }
}

// ---------------------------------------------------------------------------
// k_aggi: FUSED agg + gi per 64-node tile.
//   Phase A (agg): agg[z][m][o] = sum_n (adj[z][m][n]-0.5)*supt[z][o][n]
//                  + 0.5*colsum[z][o]     (64x128 tile, 16 K-steps, dbuf)
//   A staged via T14 split: issue loads at top of step, convert+ds_write AFTER
//   the MFMA block (vmcnt wait covered by compute).
//   -> hi/lo split into swizzled LDS panel aggls[64][256] (hi k=0..127, lo 128..255)
//   Phase B (gi): gi[m][c] = sum_k' agg_cat[m][k'] * wihc[c][k'] + bih[c]
//                  K'=384 maps to aggls chunks {0,1,2,3,0,1}; W staged dbuf.
//   c<256 -> girz bf16; c>=256 -> gin fp32.
// grid (16 m-tiles, 24 z). LDS = 48K pool + 32K aggls = 80 KB -> 2 blocks/CU.
// ---------------------------------------------------------------------------
__device__ __forceinline__ int aggls_off(int row, int k)
{
    // 16B-slot XOR swizzle: stride 512 B rows would put all rows of a column
    // in one bank group; XOR the slot with row&15 spreads 16 rows -> 2-way.
    return row*256 + (((k >> 3) ^ (row & 15)) << 3) + (k & 7);
}

__global__ __launch_bounds__(256, 2) void k_aggi(
    const float* __restrict__ adjf,    // [24][1024][1024] fp32
    const bf16_t* __restrict__ supt,   // [24][128][1024]
    const float* __restrict__ colsum,  // [24][128]
    const bf16_t* __restrict__ wihcL,  // [384][384] (layer slice, pattern B)
    const float* __restrict__ biasL,   // [384] (bih layer slice)
    bf16_t* __restrict__ girz,         // [24576][256]
    float* __restrict__ gin)           // [24576][128]
{
    __shared__ char pool[49152];               // As 16K + Bs 32K; reused as BsG
    __shared__ bf16_t aggls[64*256];           // 32 KB persistent panel
    bf16_t* As  = (bf16_t*)pool;               // [2][64*64]
    bf16_t* Bs  = (bf16_t*)(pool + 16384);     // [2][128*64]
    bf16_t* BsG = (bf16_t*)pool;               // [2][128*64] (phase B)

    const int t = threadIdx.x, lane = t & 63, w = t >> 6;
    const int wr = w >> 1, wc = w & 1;
    const int m0 = blockIdx.x * 64;
    const int z  = blockIdx.y;
    const float*  Af   = adjf + (size_t)z * 1024 * 1024 + (size_t)m0 * 1024;
    const bf16_t* Brow = supt + (size_t)z * 128 * 1024;

    // ---- Phase A: agg (T14 split A-stage) ----
    f32x4 acc[2][4] = {};
    float4 ra[4];
    stageA_issue(Af, 0, ra, w, lane);
    stage_swz<128>(Brow, 1024, 0, Bs, w, lane);
    stageA_commit(ra, As, w, lane);
    __syncthreads();
    #pragma unroll
    for (int kt = 0; kt < 16; ++kt) {
        if (kt + 1 < 16) {
            stageA_issue(Af, (kt+1)*64, ra, w, lane);               // async issue
            stage_swz<128>(Brow, 1024, (kt+1)*64, Bs + ((kt+1)&1)*8192, w, lane);
        }
        mfma_swz<2,4>(As + (kt&1)*4096, Bs + (kt&1)*8192, acc, wr, wc, lane);
        if (kt + 1 < 16)
            stageA_commit(ra, As + ((kt+1)&1)*4096, w, lane);       // wait covered
        __syncthreads();
    }

    // pool is free now: prefetch first gi weight chunk while writing aggls
    stage_swz<128>(wihcL, 384, 0, BsG, w, lane);

    // agg epilogue -> aggls (hi|lo, swizzled slots)
    #pragma unroll
    for (int i = 0; i < 2; ++i) {
        #pragma unroll
        for (int rg = 0; rg < 4; ++rg) {
            int row = wr*32 + i*16 + ((lane >> 4) * 4) + rg;
            #pragma unroll
            for (int j = 0; j < 4; ++j) {
                int o = wc*64 + j*16 + (lane & 15);
                float v = acc[i][j][rg] + 0.5f * colsum[z*128 + o];
                bf16_t hi = (bf16_t)v;
                bf16_t lo = (bf16_t)(v - (float)hi);
                aggls[aggls_off(row, o)]       = hi;
                aggls[aggls_off(row, 128 + o)] = lo;
            }
        }
    }
    __syncthreads();   // aggls visible; BsG[0] staged (vmcnt drained)

    // ---- Phase B: gi over 3 c-chunks of 128 ----
    #pragma unroll
    for (int cc = 0; cc < 3; ++cc) {
        f32x4 a2[2][4] = {};
        #pragma unroll
        for (int kt = 0; kt < 6; ++kt) {
            int it = cc*6 + kt;
            if (it + 1 < 18) {
                int nc = (it+1)/6, nk = (it+1)%6;
                stage_swz<128>(wihcL + (size_t)nc*128*384, 384, nk*64,
                               BsG + ((it+1)&1)*8192, w, lane);
            }
            const bf16_t* Bcur = BsG + (it&1)*8192;
            int akk = (kt < 4 ? kt : kt - 4) * 64;   // A chunks {0,1,2,3,0,1}
            #pragma unroll
            for (int ks = 0; ks < 64; ks += 32) {
                bf16x8 af[2], bfv[4];
                #pragma unroll
                for (int i = 0; i < 2; ++i) {
                    int row = wr*32 + i*16 + (lane & 15);
                    int ss = ((akk + ks)/8 + (lane >> 4)) ^ (lane & 15);
                    af[i] = *reinterpret_cast<const bf16x8*>(&aggls[row*256 + ss*8]);
                }
                #pragma unroll
                for (int j = 0; j < 4; ++j) {
                    int row = wc*64 + j*16 + (lane & 15);
                    int sx = (ks/8 + (lane >> 4)) ^ (lane & 7);
                    bfv[j] = *reinterpret_cast<const bf16x8*>(&Bcur[row*64 + sx*8]);
                }
                #pragma unroll
                for (int i = 0; i < 2; ++i) {
                    #pragma unroll
                    for (int j = 0; j < 4; ++j)
                        a2[i][j] = __builtin_amdgcn_mfma_f32_16x16x32_bf16(af[i], bfv[j], a2[i][j], 0, 0, 0);
                }
            }
            __syncthreads();
        }
        // gi epilogue for this c-chunk (cc uniform: dtype branch is uniform)
        #pragma unroll
        for (int j = 0; j < 4; ++j) {
            int c = cc*128 + wc*64 + j*16 + (lane & 15);
            float bv = biasL[c];
            #pragma unroll
            for (int i = 0; i < 2; ++i) {
                #pragma unroll
                for (int rg = 0; rg < 4; ++rg) {
                    int rloc = wr*32 + i*16 + ((lane >> 4) * 4) + rg;
                    size_t m = (size_t)z*1024 + m0 + rloc;
                    float v = a2[i][j][rg] + bv;
                    if (c < 256) girz[m*256 + c] = (bf16_t)v;
                    else         gin[m*128 + (c - 256)] = v;
                }
            }
        }
    }
}

// ---------------------------------------------------------------------------
// GRU gates + sum over d + relu + highway blend.
// h reconstructed exactly from xcat (hi+lo). grid (64 n-blocks of 16, 8 b).
// ---------------------------------------------------------------------------
__global__ __launch_bounds__(256) void k_gates(
    const bf16_t* __restrict__ girz, const float* __restrict__ gin,
    const bf16_t* __restrict__ ghb,
    bf16_t* xcat,                       // NOT restrict: read+write same buffer
    const float* __restrict__ tbuf,
    float* __restrict__ Xout, int write_xcat)
{
    __shared__ float ts[128*17];
    const int b = blockIdx.y, n0 = blockIdx.x * 16;
    const int tid = threadIdx.x;
    {
        int o = tid >> 1, nh = (tid & 1) * 8;
        const float* src = tbuf + ((size_t)(b*128 + o))*1024 + n0 + nh;
        float4 v0 = *reinterpret_cast<const float4*>(src);
        float4 v1 = *reinterpret_cast<const float4*>(src + 4);
        float* dst = &ts[o*17 + nh];
        dst[0]=v0.x; dst[1]=v0.y; dst[2]=v0.z; dst[3]=v0.w;
        dst[4]=v1.x; dst[5]=v1.y; dst[6]=v1.z; dst[7]=v1.w;
    }
    __syncthreads();
    #pragma unroll
    for (int p = 0; p < 8; ++p) {
        int e = p*256 + tid;
        int nn = e >> 7, o = e & 127;
        int n = n0 + nn;
        size_t rb = (size_t)(b*1024 + n);
        bf16_t* xr = xcat + rb*384;
        float h = (float)xr[o] + (float)xr[256 + o];
        const bf16_t* ghr = ghb + rb*G3;
        float g_r = (float)ghr[o], g_z = (float)ghr[128+o], g_n = (float)ghr[256+o];
        float acc = 0.0f;
        #pragma unroll
        for (int d = 0; d < 3; ++d) {
            size_t rr = (size_t)((d*8 + b)*1024 + n);
            float i_r = (float)girz[rr*256 + o];
            float i_z = (float)girz[rr*256 + 128 + o];
            float i_n = gin[rr*128 + o];
            float rg = fast_sigmoid(i_r + g_r);
            float zg = fast_sigmoid(i_z + g_z);
            float ng = fast_tanh(i_n + rg * g_n);
            acc += (1.0f - zg) * ng + zg * h;
        }
        float outv = fmaxf(acc, 0.0f);
        float tg = ts[o*17 + nn];
        float res = outv * tg + h * (1.0f - tg);
        if (Xout) Xout[(size_t)(n*8 + b)*128 + o] = res;
        if (write_xcat) {
            bf16_t hi = (bf16_t)res;
            bf16_t lo = (bf16_t)(res - (float)hi);
            xr[o] = hi; xr[128 + o] = hi; xr[256 + o] = lo;
        }
    }
}

// ---------------------------------------------------------------------------
extern "C" void kernel_launch(void* const* d_in, const int* in_sizes, int n_in,
                              void* d_out, int out_size, void* d_ws, size_t ws_size,
                              hipStream_t stream) {
    const float* inputs = (const float*)d_in[0];   // [1024,8,128]
    const float* adj    = (const float*)d_in[1];   // [3,8,1024,1024]
    const float* W      = (const float*)d_in[2];   // [2,3,128,128]
    const float* Bc     = (const float*)d_in[3];   // [2,3,128]
    const float* Wh     = (const float*)d_in[4];   // [2,128,128]
    const float* Bh     = (const float*)d_in[5];   // [2,128]
    const float* Wih    = (const float*)d_in[6];   // [2,384,128]
    const float* Whh    = (const float*)d_in[7];   // [2,384,128]
    const float* bih    = (const float*)d_in[8];   // [2,384]
    const float* bhh    = (const float*)d_in[9];   // [2,384]

    char* ws = (char*)d_ws;
    float*  tbuf   = (float*)ws;   ws += (size_t)8*128*1024*4;      // 4.19 MB
    bf16_t* xcat   = (bf16_t*)ws;  ws += (size_t)8*1024*384*2;      // 6.29 MB
    bf16_t* ghb    = (bf16_t*)ws;  ws += (size_t)NB*G3*2;           // 6.29 MB
    bf16_t* supt   = (bf16_t*)ws;  ws += (size_t)24*128*1024*2;     // 6.29 MB
    bf16_t* girz   = (bf16_t*)ws;  ws += (size_t)3*NB*256*2;        // 12.58 MB
    float*  gin    = (float*)ws;   ws += (size_t)3*NB*128*4;        // 12.58 MB
    float*  colsum2= (float*)ws;   ws += (size_t)2*24*128*4;        // 24 KB
    bf16_t* wsup   = (bf16_t*)ws;  ws += (size_t)2*896*384*2;       // 1.38 MB
    bf16_t* wihc   = (bf16_t*)ws;                                   // 1.18 MB

    // one-time preps (adj conversion fused into k_aggi; colsum zeroed in k_xcat)
    k_wprep<<<dim3(1280, 2), dim3(128), 0, stream>>>(W, Wh, Whh, Wih, wsup, wihc);
    k_xcat<<<dim3(4096), dim3(256), 0, stream>>>(inputs, xcat, colsum2);

    for (int l = 0; l < 2; ++l) {
        float* colsum = colsum2 + l*3072;
        // support (bf16 [z][o][n]) + highway t + gh (merged) + colsum (fused)
        k_sup2<<<dim3(8, 7, 8), dim3(256), 0, stream>>>(
            wsup + (size_t)l*896*384, xcat, Bc + l*3*128, Bh + l*128, bhh + l*G3,
            supt, tbuf, ghb, colsum);
        // FUSED: agg = (adj-0.5) @ support + 0.5*colsum ; gi = agg_cat @ Wih^T + bih
        k_aggi<<<dim3(16, 24), dim3(256), 0, stream>>>(
            adj, supt, colsum, wihc + (size_t)l*384*384, bih + l*G3, girz, gin);
        // gates + sum_d + relu + highway; layer0 -> xcat update, layer1 -> d_out
        k_gates<<<dim3(64, 8), dim3(256), 0, stream>>>(
            girz, gin, ghb, xcat, tbuf,
            (l == 1) ? (float*)d_out : (float*)nullptr, (l == 0) ? 1 : 0);
    }
}

// Round 6
// 285.209 us; speedup vs baseline: 1.1992x; 1.0165x over previous
//
#include <hip/hip_runtime.h>
#include <math.h>

// Problem constants (fixed by the reference)
#define N_NODES 1024
#define BATCH   8
#define FEAT    128        // F == O
#define NDIR    3
#define NB      (N_NODES*BATCH)   // 8192
#define G3      384               // 3*O

typedef __bf16 bf16_t;
using bf16x8 = __attribute__((ext_vector_type(8))) __bf16;
using bf16x4 = __attribute__((ext_vector_type(4))) __bf16;
using f32x4  = __attribute__((ext_vector_type(4))) float;

// async global->LDS 16B per lane; LDS dest must be wave-uniform base (+lane*16)
#define GLOAD_LDS16(g, l) \
    __builtin_amdgcn_global_load_lds((const __attribute__((address_space(1))) void*)(g), \
                                     (__attribute__((address_space(3))) void*)(l), 16, 0, 0)

// counted waits / raw barriers for the k_aggi software pipeline
#define WAITV0 asm volatile("s_waitcnt vmcnt(0)" ::: "memory")
#define WAITV4 asm volatile("s_waitcnt vmcnt(4)" ::: "memory")
#define BARRIER_LG asm volatile("s_waitcnt lgkmcnt(0)\n\ts_barrier" ::: "memory")
#define BARRIER_PL asm volatile("s_barrier" ::: "memory")

// ---------------------------------------------------------------------------
// Tiled MFMA GEMM helpers, 4 waves as 2x2 (wr=w>>1, wc=w&1).
// LDS tiles are [R rows][64 k] bf16 (128 B rows) with an XOR-swizzle on the
// 16B slot index: content of (row, slot) = global (row, slot ^ (row&7)).
// global_load_lds writes linearly, so the swizzle is applied by permuting the
// per-lane GLOBAL source address (both-sides-or-neither rule).
// ---------------------------------------------------------------------------
template<int R>
__device__ __forceinline__ void stage_swz(const bf16_t* __restrict__ src, int stride,
                                          int k0, bf16_t* lds, int w, int lane)
{
    #pragma unroll
    for (int q = 0; q < R/32; ++q) {
        int rbase = w*(R/4) + q*8;                 // wave-uniform
        int row = rbase + (lane >> 3);
        int seg = (lane & 7) ^ (row & 7);          // pre-swizzled source slot
        GLOAD_LDS16(src + (size_t)row*stride + k0 + seg*8,
                    (char*)lds + (size_t)rbase*128);
    }
}

// adj fp32 A-operand, split stage (T14): issue loads to regs / commit to LDS.
__device__ __forceinline__ void stageA_issue(const float* __restrict__ src, int k0,
                                             float4 (&r)[4], int w, int lane)
{
    #pragma unroll
    for (int q = 0; q < 2; ++q) {
        int row = w*16 + q*8 + (lane >> 3);
        int seg = (lane & 7) ^ (row & 7);          // source slot for this lane's LDS slot
        const float* g = src + (size_t)row*1024 + k0 + seg*8;
        r[q*2+0] = *reinterpret_cast<const float4*>(g);
        r[q*2+1] = *reinterpret_cast<const float4*>(g + 4);
    }
}

__device__ __forceinline__ void stageA_commit(const float4 (&r)[4], bf16_t* lds,
                                              int w, int lane)
{
    #pragma unroll
    for (int q = 0; q < 2; ++q) {
        int row = w*16 + q*8 + (lane >> 3);
        int s   = lane & 7;                        // LDS slot this lane fills
        float4 v0 = r[q*2+0], v1 = r[q*2+1];
        bf16x8 pk;
        pk[0]=(bf16_t)(v0.x-0.5f); pk[1]=(bf16_t)(v0.y-0.5f);
        pk[2]=(bf16_t)(v0.z-0.5f); pk[3]=(bf16_t)(v0.w-0.5f);
        pk[4]=(bf16_t)(v1.x-0.5f); pk[5]=(bf16_t)(v1.y-0.5f);
        pk[6]=(bf16_t)(v1.z-0.5f); pk[7]=(bf16_t)(v1.w-0.5f);
        *reinterpret_cast<bf16x8*>(&lds[row*64 + s*8]) = pk;   // swizzled slot
    }
}

// mfma over one 64-k chunk, reading swizzled LDS.
template<int MI, int NJ>
__device__ __forceinline__ void mfma_swz(const bf16_t* As, const bf16_t* Bs,
                                         f32x4 (&acc)[MI][NJ], int wr, int wc, int lane)
{
    #pragma unroll
    for (int ks = 0; ks < 64; ks += 32) {
        int bslot = ks/8 + (lane >> 4);            // linear slot pre-XOR
        int sx = bslot ^ (lane & 7);               // row&7 == lane&7 for all frags
        bf16x8 af[MI], bfv[NJ];
        #pragma unroll
        for (int i = 0; i < MI; ++i) {
            int row = wr*MI*16 + i*16 + (lane & 15);
            af[i] = *reinterpret_cast<const bf16x8*>(&As[row*64 + sx*8]);
        }
        #pragma unroll
        for (int j = 0; j < NJ; ++j) {
            int row = wc*NJ*16 + j*16 + (lane & 15);
            bfv[j] = *reinterpret_cast<const bf16x8*>(&Bs[row*64 + sx*8]);
        }
        #pragma unroll
        for (int i = 0; i < MI; ++i) {
            #pragma unroll
            for (int j = 0; j < NJ; ++j)
                acc[i][j] = __builtin_amdgcn_mfma_f32_16x16x32_bf16(af[i], bfv[j], acc[i][j], 0, 0, 0);
        }
    }
}

// fast transcendentals via hardware v_exp_f32 (2^x). Error ~1 ulp-class,
// negligible against the 0.25 absmax from adj bf16 quantization.
__device__ __forceinline__ float fast_sigmoid(float x)
{
    float t = __builtin_amdgcn_exp2f(-1.442695041f * x);   // e^-x
    return __builtin_amdgcn_rcpf(1.0f + t);
}
__device__ __forceinline__ float fast_tanh(float x)
{
    float ax = fabsf(x);
    float t = __builtin_amdgcn_exp2f(-2.885390082f * ax);  // e^-2|x|
    float r = (1.0f - t) * __builtin_amdgcn_rcpf(1.0f + t);
    return copysignf(r, x);
}

// ---------------------------------------------------------------------------
// Weight prep, hi/lo split concats (K'=384):
//  m<384: W -> wsup rows 0-383 (pattern A [hi|lo|hi])
//  m in [384,512): Wh -> wsup rows 384-511 (A)
//  m in [512,896): Whh -> wsup rows 512-895 (A)   [merged k_gh weights]
//  m in [896,1280): Wih -> wihc (B [hi|hi|lo])
// ---------------------------------------------------------------------------
__global__ __launch_bounds__(128) void k_wprep(
    const float* __restrict__ W, const float* __restrict__ Wh,
    const float* __restrict__ Whh, const float* __restrict__ Wih,
    bf16_t* __restrict__ wsup,    // [2][896][384]
    bf16_t* __restrict__ wihc)    // [2][384][384]
{
    int m = blockIdx.x, l = blockIdx.y, k = threadIdx.x;
    float w;
    bf16_t* dst;
    bool patB = false;
    if (m < 384) {
        int d = m >> 7, o = m & 127;
        w = W[((size_t)(l*3 + d)*128 + k)*128 + o];
        dst = wsup + ((size_t)l*896 + m)*384;
    } else if (m < 512) {
        int o = m - 384;
        w = Wh[((size_t)l*128 + k)*128 + o];
        dst = wsup + ((size_t)l*896 + m)*384;
    } else if (m < 896) {
        int c = m - 512;
        w = Whh[((size_t)l*384 + c)*128 + k];
        dst = wsup + ((size_t)l*896 + m)*384;
    } else {
        int c = m - 896;
        w = Wih[((size_t)l*384 + c)*128 + k];
        dst = wihc + ((size_t)l*384 + c)*384;
        patB = true;
    }
    bf16_t hi = (bf16_t)w;
    bf16_t lo = (bf16_t)(w - (float)hi);
    if (patB) { dst[k] = hi; dst[128 + k] = hi; dst[256 + k] = lo; }
    else      { dst[k] = hi; dst[128 + k] = lo; dst[256 + k] = hi; }
}

// ---------------------------------------------------------------------------
// x-cat build + colsum zeroing: inputs fp32 [N,B,128] -> xcat [hi|hi|lo]
// ---------------------------------------------------------------------------
__global__ __launch_bounds__(256) void k_xcat(
    const float* __restrict__ X, bf16_t* __restrict__ xcat,
    float* __restrict__ colsum2)       // [2][3072], zeroed here
{
    int idx = blockIdx.x * 256 + threadIdx.x;   // over 8192*128
    if (idx < 2*3072) colsum2[idx] = 0.0f;
    int k = idx & 127, r = idx >> 7;
    int n = r >> 3, b = r & 7;
    float v = X[idx];
    bf16_t hi = (bf16_t)v;
    bf16_t lo = (bf16_t)(v - (float)hi);
    bf16_t* dst = xcat + ((size_t)(b*1024 + n))*384 + k;
    dst[0] = hi; dst[128] = hi; dst[256] = lo;
}

// ---------------------------------------------------------------------------
// k_sup2 (128x128 tiles, 2-phase dbuf): C[m][n] = sum_k' wcat[m][k']*xcat[b][n][k']
//  m<384 : supt (+ fused colsum partials, rounded values, atomicAdd)
//  m in [384,512): tbuf (relu); m>=512: ghb (merged k_gh)
// grid (8 n-tiles, 7 m-tiles, 8 b)
// ---------------------------------------------------------------------------
__global__ __launch_bounds__(256, 2) void k_sup2(
    const bf16_t* __restrict__ Wcat,  // [896][384] (layer slice)
    const bf16_t* __restrict__ xcat,  // [8][1024][384]
    const float* __restrict__ Bcl,    // [3,128]
    const float* __restrict__ Bhl,    // [128]
    const float* __restrict__ bhhl,   // [384]
    bf16_t* __restrict__ supt,        // [24][128][1024]
    float* __restrict__ tbuf,         // [8][128][1024]
    bf16_t* __restrict__ ghb,         // [8192][384]
    float* __restrict__ colsum)       // [3072] (this layer's buffer)
{
    __shared__ bf16_t As[2][128*64];
    __shared__ bf16_t Bs[2][128*64];
    const int t = threadIdx.x, lane = t & 63, w = t >> 6;
    const int wr = w >> 1, wc = w & 1;
    const int n0 = blockIdx.x * 128;
    const int m0 = blockIdx.y * 128;
    const int b  = blockIdx.z;
    const bf16_t* Arow = Wcat + (size_t)m0 * 384;
    const bf16_t* Brow = xcat + ((size_t)b * 1024 + n0) * 384;

    f32x4 acc[4][4] = {};
    stage_swz<128>(Arow, 384, 0, As[0], w, lane);
    stage_swz<128>(Brow, 384, 0, Bs[0], w, lane);
    __syncthreads();
    #pragma unroll
    for (int kt = 0; kt < 6; ++kt) {
        if (kt + 1 < 6) {
            stage_swz<128>(Arow, 384, (kt+1)*64, As[(kt+1)&1], w, lane);
            stage_swz<128>(Brow, 384, (kt+1)*64, Bs[(kt+1)&1], w, lane);
        }
        mfma_swz<4,4>(As[kt&1], Bs[kt&1], acc, wr, wc, lane);
        __syncthreads();
    }
    #pragma unroll
    for (int i = 0; i < 4; ++i) {
        int mb = m0 + wr*64 + i*16 + ((lane >> 4) * 4);
        if (mb < 384) {
            #pragma unroll
            for (int rg = 0; rg < 4; ++rg) {
                int m = mb + rg;
                int d = m >> 7, o = m & 127;
                float bv = Bcl[d*128 + o];
                float psum = 0.0f;
                #pragma unroll
                for (int j = 0; j < 4; ++j) {
                    int n = n0 + wc*64 + j*16 + (lane & 15);
                    bf16_t sv = (bf16_t)(acc[i][j][rg] + bv);
                    supt[((size_t)((d*8 + b)*128 + o))*1024 + n] = sv;
                    psum += (float)sv;   // colsum over the ROUNDED values
                }
                // reduce over lane&15 (the 16 n-owners of this row in this wave)
                psum += __shfl_xor(psum, 1, 64);
                psum += __shfl_xor(psum, 2, 64);
                psum += __shfl_xor(psum, 4, 64);
                psum += __shfl_xor(psum, 8, 64);
                if ((lane & 15) == 0)
                    atomicAdd(&colsum[(d*8 + b)*128 + o], psum);
            }
        } else if (mb < 512) {
            #pragma unroll
            for (int j = 0; j < 4; ++j) {
                int n = n0 + wc*64 + j*16 + (lane & 15);
                #pragma unroll
                for (int rg = 0; rg < 4; ++rg) {
                    int o = mb + rg - 384;
                    tbuf[((size_t)(b*128 + o))*1024 + n] =
                        fmaxf(acc[i][j][rg] + Bhl[o], 0.0f);
                }
            }
        } else {
            #pragma unroll
            for (int j = 0; j < 4; ++j) {
                int n = n0 + wc*64 + j*16 + (lane & 15);
                int c = mb - 512;
                bf16x4 pk;
                #pragma unroll
                for (int rg = 0; rg < 4; ++rg)
                    pk[rg] = (bf16_t)(acc[i][j][rg] + bhhl[c + rg]);
                *reinterpret_cast<bf16x4*>(&ghb[((size_t)(b*1024 + n))*384 + c]) = pk;
            }
        }
    }
}

// ---------------------------------------------------------------------------
// k_aggi: FUSED agg + gi per 64-node tile, counted-vmcnt software pipeline.
//   Phase A (agg): 16 K-steps, B(LDS) depth-2, adj(reg) depth-3; one
//     WAITV4 + BARRIER_LG per step (no __syncthreads -> no vmcnt(0) drain).
//     In-order vmcnt retirement: leaving <=4 outstanding (the newest adj
//     issue, always >=4 insts) proves adj(kt+1) and B(kt+1) complete.
//   Phase B (gi): weight panels triple-buffered (3x16K = pool), depth-2,
//     WAITV4 + BARRIER_PL per step.
// grid (16 m-tiles, 24 z). LDS = 48K pool + 32K aggls = 80 KB -> 2 blocks/CU.
// ---------------------------------------------------------------------------
__device__ __forceinline__ int aggls_off(int row, int k)
{
    // 16B-slot XOR swizzle: stride 512 B rows would put all rows of a column
    // in one bank group; XOR the slot with row&15 spreads 16 rows -> 2-way.
    return row*256 + (((k >> 3) ^ (row & 15)) << 3) + (k & 7);
}

__global__ __launch_bounds__(256, 2) void k_aggi(
    const float* __restrict__ adjf,    // [24][1024][1024] fp32
    const bf16_t* __restrict__ supt,   // [24][128][1024]
    const float* __restrict__ colsum,  // [24][128]
    const bf16_t* __restrict__ wihcL,  // [384][384] (layer slice, pattern B)
    const float* __restrict__ biasL,   // [384] (bih layer slice)
    bf16_t* __restrict__ girz,         // [24576][256]
    float* __restrict__ gin)           // [24576][128]
{
    __shared__ char pool[49152];               // A: As 16K + Bs 32K; B: 3x16K
    __shared__ bf16_t aggls[64*256];           // 32 KB persistent panel
    bf16_t* As  = (bf16_t*)pool;               // [2][64*64]   (phase A)
    bf16_t* Bs  = (bf16_t*)(pool + 16384);     // [2][128*64]  (phase A)
    bf16_t* BsG = (bf16_t*)pool;               // [3][128*64]  (phase B)

    const int t = threadIdx.x, lane = t & 63, w = t >> 6;
    const int wr = w >> 1, wc = w & 1;
    const int m0 = blockIdx.x * 64;
    const int z  = blockIdx.y;
    const float*  Af   = adjf + (size_t)z * 1024 * 1024 + (size_t)m0 * 1024;
    const bf16_t* Brow = supt + (size_t)z * 128 * 1024;

    f32x4 acc[2][4] = {};
    float4 ra[2][4];                           // adj(n) lives in ra[n&1]

    // ---- Phase A prologue ----
    stage_swz<128>(Brow, 1024, 0, Bs, w, lane);           // B(0)
    stageA_issue(Af, 0, ra[0], w, lane);                  // adj(0)
    WAITV0;
    stageA_commit(ra[0], As, w, lane);                    // As[0]
    stage_swz<128>(Brow, 1024, 64, Bs + 8192, w, lane);   // B(1)
    stageA_issue(Af, 64, ra[1], w, lane);                 // adj(1)
    stageA_issue(Af, 128, ra[0], w, lane);                // adj(2)
    BARRIER_LG;                                           // publishes As[0], B(0)

    #pragma unroll
    for (int kt = 0; kt < 16; ++kt) {
        __builtin_amdgcn_s_setprio(1);
        mfma_swz<2,4>(As + (kt&1)*4096, Bs + (kt&1)*8192, acc, wr, wc, lane);
        __builtin_amdgcn_s_setprio(0);
        // wait: adj(kt+1) + own B(kt+1) complete (<=4 newest outstanding)
        if (kt <= 13)      { WAITV4; }
        else if (kt == 14) { WAITV0; }
        if (kt < 15)
            stageA_commit(ra[(kt+1)&1], As + ((kt+1)&1)*4096, w, lane);
        BARRIER_LG;        // publish As[(kt+1)&1] + B(kt+1); free buf kt&1
        if (kt + 2 < 16)
            stage_swz<128>(Brow, 1024, (kt+2)*64, Bs + (kt&1)*8192, w, lane);
        if (kt + 3 < 16)
            stageA_issue(Af, (kt+3)*64, ra[(kt+1)&1], w, lane);
    }

    // ---- transition: aggls + first gi weight panels ----
    stage_swz<128>(wihcL, 384, 0, BsG, w, lane);          // Bg(0) -> BsG[0]
    #pragma unroll
    for (int i = 0; i < 2; ++i) {
        #pragma unroll
        for (int rg = 0; rg < 4; ++rg) {
            int row = wr*32 + i*16 + ((lane >> 4) * 4) + rg;
            #pragma unroll
            for (int j = 0; j < 4; ++j) {
                int o = wc*64 + j*16 + (lane & 15);
                float v = acc[i][j][rg] + 0.5f * colsum[z*128 + o];
                bf16_t hi = (bf16_t)v;
                bf16_t lo = (bf16_t)(v - (float)hi);
                aggls[aggls_off(row, o)]       = hi;
                aggls[aggls_off(row, 128 + o)] = lo;
            }
        }
    }
    stage_swz<128>(wihcL, 384, 64, BsG + 8192, w, lane);  // Bg(1) -> BsG[1]
    WAITV4;                                               // Bg(0)+colsum done
    BARRIER_LG;                                           // publish aggls+Bg(0)

    // ---- Phase B: gi over 3 c-chunks of 128, triple-buffered weights ----
    #pragma unroll
    for (int cc = 0; cc < 3; ++cc) {
        f32x4 a2[2][4] = {};
        #pragma unroll
        for (int kt6 = 0; kt6 < 6; ++kt6) {
            const int it = cc*6 + kt6;
            const bf16_t* Bcur = BsG + (it % 3)*8192;
            int akk = (kt6 < 4 ? kt6 : kt6 - 4) * 64;   // A chunks {0,1,2,3,0,1}
            __builtin_amdgcn_s_setprio(1);
            #pragma unroll
            for (int ks = 0; ks < 64; ks += 32) {
                bf16x8 af[2], bfv[4];
                #pragma unroll
                for (int i = 0; i < 2; ++i) {
                    int row = wr*32 + i*16 + (lane & 15);
                    int ss = ((akk + ks)/8 + (lane >> 4)) ^ (lane & 15);
                    af[i] = *reinterpret_cast<const bf16x8*>(&aggls[row*256 + ss*8]);
                }
                #pragma unroll
                for (int j = 0; j < 4; ++j) {
                    int row = wc*64 + j*16 + (lane & 15);
                    int sx = (ks/8 + (lane >> 4)) ^ (lane & 7);
                    bfv[j] = *reinterpret_cast<const bf16x8*>(&Bcur[row*64 + sx*8]);
                }
                #pragma unroll
                for (int i = 0; i < 2; ++i) {
                    #pragma unroll
                    for (int j = 0; j < 4; ++j)
                        a2[i][j] = __builtin_amdgcn_mfma_f32_16x16x32_bf16(af[i], bfv[j], a2[i][j], 0, 0, 0);
                }
            }
            __builtin_amdgcn_s_setprio(0);
            if (it + 2 < 18) {                // Bg(it+2) -> third buffer (free)
                const int ni = it + 2;
                stage_swz<128>(wihcL + (size_t)(ni/6)*128*384, 384, (ni%6)*64,
                               BsG + (ni % 3)*8192, w, lane);
            }
            if (it <= 15)      { WAITV4; }    // Bg(it+1) done (newest 4 = Bg(it+2))
            else if (it == 16) { WAITV0; }
            BARRIER_PL;                       // publish Bg(it+1); free buf it%3
        }
        // gi epilogue for this c-chunk (cc uniform: dtype branch is uniform)
        #pragma unroll
        for (int j = 0; j < 4; ++j) {
            int c = cc*128 + wc*64 + j*16 + (lane & 15);
            float bv = biasL[c];
            #pragma unroll
            for (int i = 0; i < 2; ++i) {
                #pragma unroll
                for (int rg = 0; rg < 4; ++rg) {
                    int rloc = wr*32 + i*16 + ((lane >> 4) * 4) + rg;
                    size_t m = (size_t)z*1024 + m0 + rloc;
                    float v = a2[i][j][rg] + bv;
                    if (c < 256) girz[m*256 + c] = (bf16_t)v;
                    else         gin[m*128 + (c - 256)] = v;
                }
            }
        }
    }
}

// ---------------------------------------------------------------------------
// GRU gates + sum over d + relu + highway blend.
// h reconstructed exactly from xcat (hi+lo). grid (64 n-blocks of 16, 8 b).
// ---------------------------------------------------------------------------
__global__ __launch_bounds__(256) void k_gates(
    const bf16_t* __restrict__ girz, const float* __restrict__ gin,
    const bf16_t* __restrict__ ghb,
    bf16_t* xcat,                       // NOT restrict: read+write same buffer
    const float* __restrict__ tbuf,
    float* __restrict__ Xout, int write_xcat)
{
    __shared__ float ts[128*17];
    const int b = blockIdx.y, n0 = blockIdx.x * 16;
    const int tid = threadIdx.x;
    {
        int o = tid >> 1, nh = (tid & 1) * 8;
        const float* src = tbuf + ((size_t)(b*128 + o))*1024 + n0 + nh;
        float4 v0 = *reinterpret_cast<const float4*>(src);
        float4 v1 = *reinterpret_cast<const float4*>(src + 4);
        float* dst = &ts[o*17 + nh];
        dst[0]=v0.x; dst[1]=v0.y; dst[2]=v0.z; dst[3]=v0.w;
        dst[4]=v1.x; dst[5]=v1.y; dst[6]=v1.z; dst[7]=v1.w;
    }
    __syncthreads();
    #pragma unroll
    for (int p = 0; p < 8; ++p) {
        int e = p*256 + tid;
        int nn = e >> 7, o = e & 127;
        int n = n0 + nn;
        size_t rb = (size_t)(b*1024 + n);
        bf16_t* xr = xcat + rb*384;
        float h = (float)xr[o] + (float)xr[256 + o];
        const bf16_t* ghr = ghb + rb*G3;
        float g_r = (float)ghr[o], g_z = (float)ghr[128+o], g_n = (float)ghr[256+o];
        float acc = 0.0f;
        #pragma unroll
        for (int d = 0; d < 3; ++d) {
            size_t rr = (size_t)((d*8 + b)*1024 + n);
            float i_r = (float)girz[rr*256 + o];
            float i_z = (float)girz[rr*256 + 128 + o];
            float i_n = gin[rr*128 + o];
            float rg = fast_sigmoid(i_r + g_r);
            float zg = fast_sigmoid(i_z + g_z);
            float ng = fast_tanh(i_n + rg * g_n);
            acc += (1.0f - zg) * ng + zg * h;
        }
        float outv = fmaxf(acc, 0.0f);
        float tg = ts[o*17 + nn];
        float res = outv * tg + h * (1.0f - tg);
        if (Xout) Xout[(size_t)(n*8 + b)*128 + o] = res;
        if (write_xcat) {
            bf16_t hi = (bf16_t)res;
            bf16_t lo = (bf16_t)(res - (float)hi);
            xr[o] = hi; xr[128 + o] = hi; xr[256 + o] = lo;
        }
    }
}

// ---------------------------------------------------------------------------
extern "C" void kernel_launch(void* const* d_in, const int* in_sizes, int n_in,
                              void* d_out, int out_size, void* d_ws, size_t ws_size,
                              hipStream_t stream) {
    const float* inputs = (const float*)d_in[0];   // [1024,8,128]
    const float* adj    = (const float*)d_in[1];   // [3,8,1024,1024]
    const float* W      = (const float*)d_in[2];   // [2,3,128,128]
    const float* Bc     = (const float*)d_in[3];   // [2,3,128]
    const float* Wh     = (const float*)d_in[4];   // [2,128,128]
    const float* Bh     = (const float*)d_in[5];   // [2,128]
    const float* Wih    = (const float*)d_in[6];   // [2,384,128]
    const float* Whh    = (const float*)d_in[7];   // [2,384,128]
    const float* bih    = (const float*)d_in[8];   // [2,384]
    const float* bhh    = (const float*)d_in[9];   // [2,384]

    char* ws = (char*)d_ws;
    float*  tbuf   = (float*)ws;   ws += (size_t)8*128*1024*4;      // 4.19 MB
    bf16_t* xcat   = (bf16_t*)ws;  ws += (size_t)8*1024*384*2;      // 6.29 MB
    bf16_t* ghb    = (bf16_t*)ws;  ws += (size_t)NB*G3*2;           // 6.29 MB
    bf16_t* supt   = (bf16_t*)ws;  ws += (size_t)24*128*1024*2;     // 6.29 MB
    bf16_t* girz   = (bf16_t*)ws;  ws += (size_t)3*NB*256*2;        // 12.58 MB
    float*  gin    = (float*)ws;   ws += (size_t)3*NB*128*4;        // 12.58 MB
    float*  colsum2= (float*)ws;   ws += (size_t)2*24*128*4;        // 24 KB
    bf16_t* wsup   = (bf16_t*)ws;  ws += (size_t)2*896*384*2;       // 1.38 MB
    bf16_t* wihc   = (bf16_t*)ws;                                   // 1.18 MB

    // one-time preps (adj conversion fused into k_aggi; colsum zeroed in k_xcat)
    k_wprep<<<dim3(1280, 2), dim3(128), 0, stream>>>(W, Wh, Whh, Wih, wsup, wihc);
    k_xcat<<<dim3(4096), dim3(256), 0, stream>>>(inputs, xcat, colsum2);

    for (int l = 0; l < 2; ++l) {
        float* colsum = colsum2 + l*3072;
        // support (bf16 [z][o][n]) + highway t + gh (merged) + colsum (fused)
        k_sup2<<<dim3(8, 7, 8), dim3(256), 0, stream>>>(
            wsup + (size_t)l*896*384, xcat, Bc + l*3*128, Bh + l*128, bhh + l*G3,
            supt, tbuf, ghb, colsum);
        // FUSED: agg = (adj-0.5) @ support + 0.5*colsum ; gi = agg_cat @ Wih^T + bih
        k_aggi<<<dim3(16, 24), dim3(256), 0, stream>>>(
            adj, supt, colsum, wihc + (size_t)l*384*384, bih + l*G3, girz, gin);
        // gates + sum_d + relu + highway; layer0 -> xcat update, layer1 -> d_out
        k_gates<<<dim3(64, 8), dim3(256), 0, stream>>>(
            girz, gin, ghb, xcat, tbuf,
            (l == 1) ? (float*)d_out : (float*)nullptr, (l == 0) ? 1 : 0);
    }
}